// Round 1
// baseline (526.187 us; speedup 1.0000x reference)
//
#include <hip/hip_runtime.h>
#include <hip/hip_bf16.h>
#include <math.h>

#define D 128
#define EPSV 1e-5f

// ---------------- generic tiled matmul: out = act(x @ w + b) ----------------
// x: [nrows, ldx] (uses cols [0,K)), w: [K, dout], b: [dout] or null
template<bool RELU>
__global__ __launch_bounds__(256)
void mm_kernel(const float* __restrict__ x, int ldx,
               const float* __restrict__ w, int dout,
               const float* __restrict__ b,
               float* __restrict__ out,
               int nrows, int K)
{
    __shared__ float xs[64][68];   // 64 rows x 64 k (+4 pad, keeps float4 align)
    __shared__ float ws[64][64];   // 64 k x 64 cols
    const int tid = threadIdx.x;
    const int tx = tid & 15, ty = tid >> 4;
    const int R0 = blockIdx.x * 64;
    const int C0 = blockIdx.y * 64;

    float acc[4][4] = {};

    for (int kt = 0; kt < K; kt += 64) {
        #pragma unroll
        for (int it = 0; it < 4; ++it) {
            int idx = tid + it * 256;              // 0..1023
            int r = idx >> 4, kq = (idx & 15) << 2;
            int gr = R0 + r; if (gr >= nrows) gr = nrows - 1;
            float4 v = *reinterpret_cast<const float4*>(&x[(size_t)gr * ldx + kt + kq]);
            *reinterpret_cast<float4*>(&xs[r][kq]) = v;
        }
        #pragma unroll
        for (int it = 0; it < 4; ++it) {
            int idx = tid + it * 256;
            int k = idx >> 4, cq = (idx & 15) << 2;
            float4 v = *reinterpret_cast<const float4*>(&w[(size_t)(kt + k) * dout + C0 + cq]);
            *reinterpret_cast<float4*>(&ws[k][cq]) = v;
        }
        __syncthreads();
        #pragma unroll
        for (int k = 0; k < 64; k += 4) {
            float4 xv[4];
            #pragma unroll
            for (int r = 0; r < 4; ++r)
                xv[r] = *reinterpret_cast<const float4*>(&xs[ty * 4 + r][k]);
            #pragma unroll
            for (int kk = 0; kk < 4; ++kk) {
                float wv[4];
                #pragma unroll
                for (int c = 0; c < 4; ++c) wv[c] = ws[k + kk][tx * 4 + c];
                #pragma unroll
                for (int r = 0; r < 4; ++r) {
                    float xvk = (&xv[r].x)[kk];
                    #pragma unroll
                    for (int c = 0; c < 4; ++c)
                        acc[r][c] = fmaf(xvk, wv[c], acc[r][c]);
                }
            }
        }
        __syncthreads();
    }

    #pragma unroll
    for (int r = 0; r < 4; ++r) {
        int gr = R0 + ty * 4 + r;
        if (gr < nrows) {
            float4 o;
            #pragma unroll
            for (int c = 0; c < 4; ++c) {
                float val = acc[r][c];
                if (b) val += b[C0 + tx * 4 + c];
                if (RELU) val = fmaxf(val, 0.f);
                (&o.x)[c] = val;
            }
            *reinterpret_cast<float4*>(&out[(size_t)gr * dout + C0 + tx * 4]) = o;
        }
    }
}

// ---------------- graph prep ----------------
__global__ void deg_count_kernel(const int* __restrict__ dst, int* __restrict__ deg, int E)
{
    int e = blockIdx.x * blockDim.x + threadIdx.x;
    if (e < E) atomicAdd(&deg[dst[e]], 1);
}

__global__ __launch_bounds__(1024)
void scan_kernel(const int* __restrict__ deg, int* __restrict__ row_start,
                 int* __restrict__ cursor, int n)
{
    __shared__ int wsum[16];
    const int tid = threadIdx.x, lane = tid & 63, wid = tid >> 6;
    int carry = 0;
    for (int base = 0; base < n; base += 1024) {
        int i = base + tid;
        int v = (i < n) ? deg[i] : 0;
        int xv = v;
        #pragma unroll
        for (int off = 1; off < 64; off <<= 1) {
            int y = __shfl_up(xv, off);
            if (lane >= off) xv += y;
        }
        if (lane == 63) wsum[wid] = xv;
        __syncthreads();
        if (wid == 0) {
            int sv = (lane < 16) ? wsum[lane] : 0;
            #pragma unroll
            for (int off = 1; off < 16; off <<= 1) {
                int y = __shfl_up(sv, off);
                if (lane >= off) sv += y;
            }
            if (lane < 16) wsum[lane] = sv;
        }
        __syncthreads();
        int woff = (wid > 0) ? wsum[wid - 1] : 0;
        int excl = carry + woff + xv - v;
        if (i < n) { row_start[i] = excl; cursor[i] = excl; }
        int total = wsum[15];
        carry += total;
        __syncthreads();
    }
    if (tid == 0) row_start[n] = carry;
}

__global__ void fill_kernel(const int* __restrict__ src, const int* __restrict__ dst,
                            int* __restrict__ cursor, int* __restrict__ csr_src, int E)
{
    int e = blockIdx.x * blockDim.x + threadIdx.x;
    if (e < E) {
        int d = dst[e];
        int pos = atomicAdd(&cursor[d], 1);
        csr_src[pos] = src[e];
    }
}

__global__ void dinv_kernel(const int* __restrict__ deg, float* __restrict__ dinv, int n)
{
    int i = blockIdx.x * blockDim.x + threadIdx.x;
    if (i < n) {
        int d = deg[i];
        dinv[i] = (d > 0) ? rsqrtf((float)d) : 0.f;
    }
}

// ---------------- GCN gather: local_out = segsum(coef * xw[src]) + b_gcn ----------------
__global__ __launch_bounds__(256)
void gcn_gather_kernel(const float* __restrict__ xw,
                       const int* __restrict__ row_start,
                       const int* __restrict__ csr_src,
                       const float* __restrict__ dinv,
                       const float* __restrict__ b_gcn,
                       float* __restrict__ local_out, int n)
{
    const int wid = threadIdx.x >> 6, lane = threadIdx.x & 63;
    const int node = blockIdx.x * 4 + wid;
    if (node >= n) return;
    const int s0 = row_start[node], s1 = row_start[node + 1];
    const float dn = dinv[node];
    const int d0 = lane * 2;
    float a0 = 0.f, a1 = 0.f;
    for (int j = s0; j < s1; ++j) {
        int s = csr_src[j];
        float c = dn * dinv[s];
        float2 xv = *reinterpret_cast<const float2*>(&xw[(size_t)s * D + d0]);
        a0 = fmaf(c, xv.x, a0);
        a1 = fmaf(c, xv.y, a1);
    }
    float2 o = make_float2(a0 + b_gcn[d0], a1 + b_gcn[d0 + 1]);
    *reinterpret_cast<float2*>(&local_out[(size_t)node * D + d0]) = o;
}

__device__ __forceinline__ float wave_sum(float v)
{
    #pragma unroll
    for (int off = 1; off <= 32; off <<= 1) v += __shfl_xor(v, off);
    return v;
}

// ---------------- fused: attention + beta gate + combine + LayerNorm1 ----------------
__global__ __launch_bounds__(256)
void attn_combine_ln_kernel(const float* __restrict__ qb,
                            const float* __restrict__ kb,
                            const float* __restrict__ vb,
                            const float* __restrict__ x_r,
                            const float* __restrict__ local_out,
                            const int* __restrict__ row_start,
                            const int* __restrict__ csr_src,
                            const float* __restrict__ w_beta,
                            const float* __restrict__ g1, const float* __restrict__ b1,
                            const float* __restrict__ local_w, const float* __restrict__ global_w,
                            float* __restrict__ h_ln, int n)
{
    const int wid = threadIdx.x >> 6, lane = threadIdx.x & 63;
    const int node = blockIdx.x * 4 + wid;
    if (node >= n) return;
    const int d0 = lane * 2;
    const float2 qv = *reinterpret_cast<const float2*>(&qb[(size_t)node * D + d0]);

    float m = -INFINITY, s = 0.f, acc0 = 0.f, acc1 = 0.f;
    const int e0 = row_start[node], e1 = row_start[node + 1];
    const float scale = 0.17677669529663687f;  // 1/sqrt(32)

    for (int j = e0; j < e1; ++j) {
        int sidx = csr_src[j];
        float2 kv = *reinterpret_cast<const float2*>(&kb[(size_t)sidx * D + d0]);
        float p = qv.x * kv.x + qv.y * kv.y;
        // reduce within 16-lane head group (head = lane/16, C=32 -> 2 per lane)
        p += __shfl_xor(p, 1);
        p += __shfl_xor(p, 2);
        p += __shfl_xor(p, 4);
        p += __shfl_xor(p, 8);
        float alpha = p * scale;
        float mnew = fmaxf(m, alpha);
        float corr = __expf(m - mnew);     // 0 when m == -inf
        float wgt  = __expf(alpha - mnew);
        float2 vv = *reinterpret_cast<const float2*>(&vb[(size_t)sidx * D + d0]);
        s   = s * corr + wgt;
        acc0 = fmaf(acc0, corr, wgt * vv.x);
        acc1 = fmaf(acc1, corr, wgt * vv.y);
        m = mnew;
    }
    const float denom = fmaxf(s, 1e-16f);
    const float og0 = acc0 / denom, og1 = acc1 / denom;

    const float2 xr = *reinterpret_cast<const float2*>(&x_r[(size_t)node * D + d0]);

    // beta = sigmoid([out_g, x_r, out_g - x_r] @ w_beta)
    float part = og0 * w_beta[d0] + og1 * w_beta[d0 + 1]
               + xr.x * w_beta[D + d0] + xr.y * w_beta[D + d0 + 1]
               + (og0 - xr.x) * w_beta[2 * D + d0] + (og1 - xr.y) * w_beta[2 * D + d0 + 1];
    part = wave_sum(part);
    const float beta = 1.f / (1.f + __expf(-part));

    const float go0 = beta * xr.x + (1.f - beta) * og0;
    const float go1 = beta * xr.y + (1.f - beta) * og1;

    const float2 lo = *reinterpret_cast<const float2*>(&local_out[(size_t)node * D + d0]);
    const float lw = local_w[0], gw = global_w[0];
    float t0 = 2.f * (lw * lo.x + gw * go0);
    float t1 = 2.f * (lw * lo.y + gw * go1);

    // LayerNorm(t, g1, b1)
    float mu = wave_sum(t0 + t1) * (1.f / 128.f);
    float dv0 = t0 - mu, dv1 = t1 - mu;
    float var = wave_sum(dv0 * dv0 + dv1 * dv1) * (1.f / 128.f);
    float rs = rsqrtf(var + EPSV);
    float o0 = dv0 * rs * g1[d0] + b1[d0];
    float o1 = dv1 * rs * g1[d0 + 1] + b1[d0 + 1];
    *reinterpret_cast<float2*>(&h_ln[(size_t)node * D + d0]) = make_float2(o0, o1);
}

// ---------------- final: LayerNorm(out0 + h_ln, g2, b2) ----------------
__global__ __launch_bounds__(256)
void final_ln_kernel(const float* __restrict__ out0, const float* __restrict__ hln,
                     const float* __restrict__ g2, const float* __restrict__ b2,
                     float* __restrict__ out, int n)
{
    const int wid = threadIdx.x >> 6, lane = threadIdx.x & 63;
    const int node = blockIdx.x * 4 + wid;
    if (node >= n) return;
    const int d0 = lane * 2;
    float2 a = *reinterpret_cast<const float2*>(&out0[(size_t)node * D + d0]);
    float2 b = *reinterpret_cast<const float2*>(&hln[(size_t)node * D + d0]);
    float t0 = a.x + b.x, t1 = a.y + b.y;
    float mu = wave_sum(t0 + t1) * (1.f / 128.f);
    float dv0 = t0 - mu, dv1 = t1 - mu;
    float var = wave_sum(dv0 * dv0 + dv1 * dv1) * (1.f / 128.f);
    float rs = rsqrtf(var + EPSV);
    float o0 = dv0 * rs * g2[d0] + b2[d0];
    float o1 = dv1 * rs * g2[d0 + 1] + b2[d0 + 1];
    *reinterpret_cast<float2*>(&out[(size_t)node * D + d0]) = make_float2(o0, o1);
}

// ---------------- launch ----------------
extern "C" void kernel_launch(void* const* d_in, const int* in_sizes, int n_in,
                              void* d_out, int out_size, void* d_ws, size_t ws_size,
                              hipStream_t stream)
{
    const float* x      = (const float*)d_in[0];
    const int*   ei     = (const int*)d_in[1];
    const float* w_gcn  = (const float*)d_in[2];
    const float* b_gcn  = (const float*)d_in[3];
    const float* wq     = (const float*)d_in[4];
    const float* bq     = (const float*)d_in[5];
    const float* wk     = (const float*)d_in[6];
    const float* bk     = (const float*)d_in[7];
    const float* wv     = (const float*)d_in[8];
    const float* bv     = (const float*)d_in[9];
    const float* w_skip = (const float*)d_in[10];
    const float* b_skip = (const float*)d_in[11];
    const float* w_beta = (const float*)d_in[12];
    const float* g1     = (const float*)d_in[13];
    const float* b1     = (const float*)d_in[14];
    const float* g2     = (const float*)d_in[15];
    const float* b2     = (const float*)d_in[16];
    const float* w_rel  = (const float*)d_in[17];
    const float* w_root = (const float*)d_in[18];
    const float* lw     = (const float*)d_in[19];
    const float* gw     = (const float*)d_in[20];

    const int N = in_sizes[0] / D;
    const int E = in_sizes[1] / 2;
    const int* src = ei;
    const int* dst = ei + E;

    const size_t ND = (size_t)N * D;
    float* ws_f  = (float*)d_ws;
    float* xw    = ws_f + 0 * ND;
    float* qb    = ws_f + 1 * ND;
    float* kb    = ws_f + 2 * ND;
    float* vb    = ws_f + 3 * ND;
    float* xr    = ws_f + 4 * ND;
    float* lout  = ws_f + 5 * ND;
    float* hln   = ws_f + 6 * ND;
    float* fbuf  = ws_f + 0 * ND;   // [N,256] aliases xw+qb (dead by FFN time)
    float* out0  = ws_f + 2 * ND;   // aliases kb (dead)
    int*  ibase     = (int*)(ws_f + 7 * ND);
    int*  deg       = ibase;
    int*  row_start = ibase + N;          // N+1 entries
    int*  cursor    = ibase + 2 * N + 1;
    int*  csr_src   = ibase + 3 * N + 1;
    float* dinv     = (float*)(csr_src + E);

    float* out = (float*)d_out;

    // ---- graph prep ----
    hipMemsetAsync(deg, 0, (size_t)N * sizeof(int), stream);
    deg_count_kernel<<<dim3((E + 255) / 256), dim3(256), 0, stream>>>(dst, deg, E);
    scan_kernel<<<dim3(1), dim3(1024), 0, stream>>>(deg, row_start, cursor, N);
    fill_kernel<<<dim3((E + 255) / 256), dim3(256), 0, stream>>>(src, dst, cursor, csr_src, E);
    dinv_kernel<<<dim3((N + 255) / 256), dim3(256), 0, stream>>>(deg, dinv, N);

    // ---- dense projections ----
    dim3 mmb(256);
    dim3 g128((N + 63) / 64, 2);
    mm_kernel<false><<<g128, mmb, 0, stream>>>(x, D, w_gcn, D, nullptr, xw, N, D);
    mm_kernel<false><<<g128, mmb, 0, stream>>>(x, D, wq, D, bq, qb, N, D);
    mm_kernel<false><<<g128, mmb, 0, stream>>>(x, D, wk, D, bk, kb, N, D);
    mm_kernel<false><<<g128, mmb, 0, stream>>>(x, D, wv, D, bv, vb, N, D);
    mm_kernel<false><<<g128, mmb, 0, stream>>>(x, D, w_skip, D, b_skip, xr, N, D);

    // ---- edge phases ----
    dim3 nodeb(256);
    dim3 nodeg((N + 3) / 4);
    gcn_gather_kernel<<<nodeg, nodeb, 0, stream>>>(xw, row_start, csr_src, dinv, b_gcn, lout, N);
    attn_combine_ln_kernel<<<nodeg, nodeb, 0, stream>>>(qb, kb, vb, xr, lout, row_start, csr_src,
                                                        w_beta, g1, b1, lw, gw, hln, N);

    // ---- FFN ----
    dim3 g256((N + 63) / 64, 4);
    mm_kernel<true ><<<g256, mmb, 0, stream>>>(hln, D, w_rel, 2 * D, nullptr, fbuf, N, D);
    mm_kernel<false><<<g128, mmb, 0, stream>>>(fbuf, 2 * D, w_root, D, nullptr, out0, N, 2 * D);

    // ---- final LN ----
    final_ln_kernel<<<nodeg, nodeb, 0, stream>>>(out0, hln, g2, b2, out, N);
}

// Round 2
// 316.615 us; speedup vs baseline: 1.6619x; 1.6619x over previous
//
#include <hip/hip_runtime.h>
#include <math.h>

#define D 128
#define EPSV 1e-5f

typedef unsigned short ushort_t;
typedef __attribute__((ext_vector_type(8))) short short8v;
typedef __attribute__((ext_vector_type(4))) float f32x4;

__device__ __forceinline__ float bf2f(unsigned u) {
    return __uint_as_float(u << 16);
}
__device__ __forceinline__ ushort_t f2bf(float f) {
    unsigned u = __float_as_uint(f);
    unsigned r = (u + 0x7fffu + ((u >> 16) & 1u)) >> 16;   // RNE
    return (ushort_t)r;
}

// =================== bf16 MFMA GEMM ===================
// A: [M,K] bf16 row-major. Bt: [Nout,K] bf16 (transposed weights).
// Tile 128x64, 4 waves (2Mx2N), 16x16x32 MFMA, K staged in 128-chunks,
// XOR-swizzled LDS (chunk16 ^= row&7) to kill the stride-256B bank conflict.
// MODE: 0 = f32 out, 1 = bf16 out, 2 = bf16 out + relu,
//       3 = projection epilogue (pack_kvx / qb_bf / xr by column block)
template<int MODE>
__global__ __launch_bounds__(256)
void gemm_mfma(const ushort_t* __restrict__ A,
               const ushort_t* __restrict__ Bt,
               const float* __restrict__ bias,
               void* __restrict__ outp, int M, int K, int Nout,
               ushort_t* __restrict__ pack_kvx,
               ushort_t* __restrict__ qb_bf,
               float* __restrict__ xr)
{
    __shared__ ushort_t As[128 * 128];
    __shared__ ushort_t Bs[64 * 128];
    const int tid  = threadIdx.x;
    const int lane = tid & 63, wid = tid >> 6;
    const int wr = wid >> 1, wc = wid & 1;
    const int C0 = blockIdx.x * 64;
    const int R0 = blockIdx.y * 128;

    f32x4 acc[4][2] = {};

    for (int kt = 0; kt < K; kt += 128) {
        #pragma unroll
        for (int it = 0; it < 8; ++it) {            // A tile: 2048 x 16B chunks
            int linear = tid + it * 256;
            int row = linear >> 4, c16 = linear & 15;
            int gr = R0 + row; if (gr >= M) gr = M - 1;
            int sw = c16 ^ (row & 7);
            *reinterpret_cast<short8v*>(&As[row * 128 + sw * 8]) =
                *reinterpret_cast<const short8v*>(&A[(size_t)gr * K + kt + c16 * 8]);
        }
        #pragma unroll
        for (int it = 0; it < 4; ++it) {            // B tile: 1024 x 16B chunks
            int linear = tid + it * 256;
            int row = linear >> 4, c16 = linear & 15;
            int sw = c16 ^ (row & 7);
            *reinterpret_cast<short8v*>(&Bs[row * 128 + sw * 8]) =
                *reinterpret_cast<const short8v*>(&Bt[(size_t)(C0 + row) * K + kt + c16 * 8]);
        }
        __syncthreads();
        #pragma unroll
        for (int ks = 0; ks < 4; ++ks) {
            short8v av[4], bv[2];
            #pragma unroll
            for (int r = 0; r < 4; ++r) {
                int row = wr * 64 + r * 16 + (lane & 15);
                int chunk = (ks * 4 + (lane >> 4)) ^ (row & 7);
                av[r] = *reinterpret_cast<const short8v*>(&As[row * 128 + chunk * 8]);
            }
            #pragma unroll
            for (int c = 0; c < 2; ++c) {
                int row = wc * 32 + c * 16 + (lane & 15);
                int chunk = (ks * 4 + (lane >> 4)) ^ (row & 7);
                bv[c] = *reinterpret_cast<const short8v*>(&Bs[row * 128 + chunk * 8]);
            }
            #pragma unroll
            for (int r = 0; r < 4; ++r)
                #pragma unroll
                for (int c = 0; c < 2; ++c)
                    acc[r][c] = __builtin_amdgcn_mfma_f32_16x16x32_bf16(av[r], bv[c], acc[r][c], 0, 0, 0);
        }
        __syncthreads();
    }

    // epilogue: D row = (lane>>4)*4 + i, col = lane&15  (verified layout)
    const int dest = C0 >> 7;                 // MODE 3: whole block is one dest
    #pragma unroll
    for (int r = 0; r < 4; ++r) {
        int grb = R0 + wr * 64 + r * 16 + (lane >> 4) * 4;
        #pragma unroll
        for (int i = 0; i < 4; ++i) {
            int gr = grb + i;
            if (gr < M) {
                #pragma unroll
                for (int c = 0; c < 2; ++c) {
                    int gc = C0 + wc * 32 + c * 16 + (lane & 15);
                    float v = acc[r][c][i];
                    if (bias) v += bias[gc];
                    if (MODE == 2) v = fmaxf(v, 0.f);
                    if (MODE == 0) {
                        ((float*)outp)[(size_t)gr * Nout + gc] = v;
                    } else if (MODE == 1 || MODE == 2) {
                        ((ushort_t*)outp)[(size_t)gr * Nout + gc] = f2bf(v);
                    } else { // MODE 3
                        int gcl = gc & 127;
                        if (dest == 0)       pack_kvx[(size_t)gr * 384 + 256 + gcl] = f2bf(v); // xw
                        else if (dest == 1)  qb_bf[(size_t)gr * 128 + gcl] = f2bf(v);          // q
                        else if (dest == 2)  pack_kvx[(size_t)gr * 384 + gcl] = f2bf(v);       // k
                        else if (dest == 3)  pack_kvx[(size_t)gr * 384 + 128 + gcl] = f2bf(v); // v
                        else                 xr[(size_t)gr * 128 + gcl] = v;                   // skip
                    }
                }
            }
        }
    }
}

// =================== conversions / packing ===================
__global__ void cvt_bf16_kernel(const float* __restrict__ in, ushort_t* __restrict__ out, int n4)
{
    int i = blockIdx.x * blockDim.x + threadIdx.x;
    if (i < n4) {
        float4 v = reinterpret_cast<const float4*>(in)[i];
        uint2 o;
        o.x = (unsigned)f2bf(v.x) | ((unsigned)f2bf(v.y) << 16);
        o.y = (unsigned)f2bf(v.z) | ((unsigned)f2bf(v.w) << 16);
        reinterpret_cast<uint2*>(out)[i] = o;
    }
}

__global__ void pack_weights_kernel(const float* __restrict__ wg, const float* __restrict__ wq,
                                    const float* __restrict__ wk, const float* __restrict__ wv,
                                    const float* __restrict__ wsk,
                                    const float* __restrict__ bq, const float* __restrict__ bk,
                                    const float* __restrict__ bv, const float* __restrict__ bsk,
                                    const float* __restrict__ wrel, const float* __restrict__ wroot,
                                    ushort_t* __restrict__ wt_all, ushort_t* __restrict__ wt_rel,
                                    ushort_t* __restrict__ wt_root, float* __restrict__ bias_all)
{
    int i = blockIdx.x * 256 + threadIdx.x;
    if (i < 640 * 128) {                         // wt_all[n][k] = W[k][n], 5 concat weights
        int n = i >> 7, k = i & 127;
        const float* srcs[5] = {wg, wq, wk, wv, wsk};
        wt_all[i] = f2bf(srcs[n >> 7][k * 128 + (n & 127)]);
    } else if (i < 640 * 128 + 256 * 128) {      // wt_rel[n][k] = w_rel[k][n]
        int j = i - 640 * 128;
        int n = j >> 7, k = j & 127;
        wt_rel[j] = f2bf(wrel[k * 256 + n]);
    } else if (i < 640 * 128 + 256 * 128 + 128 * 256) {  // wt_root[n][k] = w_root[k][n]
        int j = i - (640 * 128 + 256 * 128);
        int n = j >> 8, k = j & 255;
        wt_root[j] = f2bf(wroot[k * 128 + n]);
    } else if (i < 640 * 128 + 256 * 128 + 128 * 256 + 640) {
        int n = i - (640 * 128 + 256 * 128 + 128 * 256);
        float b = 0.f;                           // cols [0,128) = gcn: bias added later
        if (n >= 128) {
            const float* bs[4] = {bq, bk, bv, bsk};
            b = bs[(n - 128) >> 7][n & 127];
        }
        bias_all[n] = b;
    }
}

// =================== graph prep ===================
__global__ void deg_count_kernel(const int* __restrict__ dst, int* __restrict__ deg, int E)
{
    int e = blockIdx.x * blockDim.x + threadIdx.x;
    if (e < E) atomicAdd(&deg[dst[e]], 1);
}

__global__ __launch_bounds__(1024)
void scan_kernel(const int* __restrict__ deg, int* __restrict__ row_start,
                 int* __restrict__ cursor, int n)
{
    __shared__ int wsum[16];
    const int tid = threadIdx.x, lane = tid & 63, wid = tid >> 6;
    int carry = 0;
    for (int base = 0; base < n; base += 1024) {
        int i = base + tid;
        int v = (i < n) ? deg[i] : 0;
        int xv = v;
        #pragma unroll
        for (int off = 1; off < 64; off <<= 1) {
            int y = __shfl_up(xv, off);
            if (lane >= off) xv += y;
        }
        if (lane == 63) wsum[wid] = xv;
        __syncthreads();
        if (wid == 0) {
            int sv = (lane < 16) ? wsum[lane] : 0;
            #pragma unroll
            for (int off = 1; off < 16; off <<= 1) {
                int y = __shfl_up(sv, off);
                if (lane >= off) sv += y;
            }
            if (lane < 16) wsum[lane] = sv;
        }
        __syncthreads();
        int woff = (wid > 0) ? wsum[wid - 1] : 0;
        int excl = carry + woff + xv - v;
        if (i < n) { row_start[i] = excl; cursor[i] = excl; }
        int total = wsum[15];
        carry += total;
        __syncthreads();
    }
    if (tid == 0) row_start[n] = carry;
}

__global__ void fill_kernel(const int* __restrict__ src, const int* __restrict__ dst,
                            int* __restrict__ cursor, int* __restrict__ csr_src, int E)
{
    int e = blockIdx.x * blockDim.x + threadIdx.x;
    if (e < E) {
        int d = dst[e];
        int pos = atomicAdd(&cursor[d], 1);
        csr_src[pos] = src[e];
    }
}

__global__ void dinv_kernel(const int* __restrict__ deg, float* __restrict__ dinv, int n)
{
    int i = blockIdx.x * blockDim.x + threadIdx.x;
    if (i < n) {
        int d = deg[i];
        dinv[i] = (d > 0) ? rsqrtf((float)d) : 0.f;
    }
}

__device__ __forceinline__ float wave_sum(float v)
{
    #pragma unroll
    for (int off = 1; off <= 32; off <<= 1) v += __shfl_xor(v, off);
    return v;
}

// ===== fused: GCN gather + attention + beta gate + combine + LayerNorm1 =====
// pack: [N][384] bf16 rows = k(128) | v(128) | xw(128)
__global__ __launch_bounds__(256)
void edge_fused_kernel(const ushort_t* __restrict__ pack,
                       const ushort_t* __restrict__ qbf,
                       const float* __restrict__ x_r,
                       const int* __restrict__ row_start,
                       const int* __restrict__ csr_src,
                       const float* __restrict__ dinv,
                       const float* __restrict__ b_gcn,
                       const float* __restrict__ w_beta,
                       const float* __restrict__ g1, const float* __restrict__ b1,
                       const float* __restrict__ local_w, const float* __restrict__ global_w,
                       float* __restrict__ hln, ushort_t* __restrict__ hln_bf, int n)
{
    const int wid = threadIdx.x >> 6, lane = threadIdx.x & 63;
    const int node = blockIdx.x * 4 + wid;
    if (node >= n) return;
    const int d0 = lane * 2;

    unsigned qu = *reinterpret_cast<const unsigned*>(&qbf[(size_t)node * 128 + d0]);
    const float q0 = bf2f(qu & 0xffffu), q1 = bf2f(qu >> 16);

    float m = -INFINITY, s = 0.f, va0 = 0.f, va1 = 0.f, ga0 = 0.f, ga1 = 0.f;
    const int e0 = row_start[node], e1 = row_start[node + 1];
    const float dn = dinv[node];
    const float scale = 0.17677669529663687f;  // 1/sqrt(32)

    for (int j = e0; j < e1; ++j) {
        int sidx = csr_src[j];
        const ushort_t* prow = pack + (size_t)sidx * 384;
        unsigned ku = *reinterpret_cast<const unsigned*>(&prow[d0]);
        float p = q0 * bf2f(ku & 0xffffu) + q1 * bf2f(ku >> 16);
        p += __shfl_xor(p, 1);
        p += __shfl_xor(p, 2);
        p += __shfl_xor(p, 4);
        p += __shfl_xor(p, 8);
        float alpha = p * scale;
        float mnew = fmaxf(m, alpha);
        float corr = __expf(m - mnew);
        float wgt  = __expf(alpha - mnew);
        unsigned vu = *reinterpret_cast<const unsigned*>(&prow[128 + d0]);
        unsigned xu = *reinterpret_cast<const unsigned*>(&prow[256 + d0]);
        float c = dn * dinv[sidx];
        s   = s * corr + wgt;
        va0 = fmaf(va0, corr, wgt * bf2f(vu & 0xffffu));
        va1 = fmaf(va1, corr, wgt * bf2f(vu >> 16));
        ga0 = fmaf(c, bf2f(xu & 0xffffu), ga0);
        ga1 = fmaf(c, bf2f(xu >> 16), ga1);
        m = mnew;
    }
    const float denom = fmaxf(s, 1e-16f);
    const float og0 = va0 / denom, og1 = va1 / denom;

    const float2 xr2 = *reinterpret_cast<const float2*>(&x_r[(size_t)node * 128 + d0]);
    const float lo0 = ga0 + b_gcn[d0], lo1 = ga1 + b_gcn[d0 + 1];

    float part = og0 * w_beta[d0] + og1 * w_beta[d0 + 1]
               + xr2.x * w_beta[128 + d0] + xr2.y * w_beta[128 + d0 + 1]
               + (og0 - xr2.x) * w_beta[256 + d0] + (og1 - xr2.y) * w_beta[256 + d0 + 1];
    part = wave_sum(part);
    const float beta = 1.f / (1.f + __expf(-part));

    const float go0 = beta * xr2.x + (1.f - beta) * og0;
    const float go1 = beta * xr2.y + (1.f - beta) * og1;

    const float lw = local_w[0], gw = global_w[0];
    float t0 = 2.f * (lw * lo0 + gw * go0);
    float t1 = 2.f * (lw * lo1 + gw * go1);

    float mu = wave_sum(t0 + t1) * (1.f / 128.f);
    float dv0 = t0 - mu, dv1 = t1 - mu;
    float var = wave_sum(dv0 * dv0 + dv1 * dv1) * (1.f / 128.f);
    float rs = rsqrtf(var + EPSV);
    float o0 = dv0 * rs * g1[d0] + b1[d0];
    float o1 = dv1 * rs * g1[d0 + 1] + b1[d0 + 1];
    *reinterpret_cast<float2*>(&hln[(size_t)node * 128 + d0]) = make_float2(o0, o1);
    *reinterpret_cast<unsigned*>(&hln_bf[(size_t)node * 128 + d0]) =
        (unsigned)f2bf(o0) | ((unsigned)f2bf(o1) << 16);
}

// =================== final: LayerNorm(out0 + hln) ===================
__global__ __launch_bounds__(256)
void final_ln_kernel(const float* __restrict__ out0, const float* __restrict__ hln,
                     const float* __restrict__ g2, const float* __restrict__ b2,
                     float* __restrict__ out, int n)
{
    const int wid = threadIdx.x >> 6, lane = threadIdx.x & 63;
    const int node = blockIdx.x * 4 + wid;
    if (node >= n) return;
    const int d0 = lane * 2;
    float2 a = *reinterpret_cast<const float2*>(&out0[(size_t)node * 128 + d0]);
    float2 b = *reinterpret_cast<const float2*>(&hln[(size_t)node * 128 + d0]);
    float t0 = a.x + b.x, t1 = a.y + b.y;
    float mu = wave_sum(t0 + t1) * (1.f / 128.f);
    float dv0 = t0 - mu, dv1 = t1 - mu;
    float var = wave_sum(dv0 * dv0 + dv1 * dv1) * (1.f / 128.f);
    float rs = rsqrtf(var + EPSV);
    float o0 = dv0 * rs * g2[d0] + b2[d0];
    float o1 = dv1 * rs * g2[d0 + 1] + b2[d0 + 1];
    *reinterpret_cast<float2*>(&out[(size_t)node * 128 + d0]) = make_float2(o0, o1);
}

// =================== launch ===================
extern "C" void kernel_launch(void* const* d_in, const int* in_sizes, int n_in,
                              void* d_out, int out_size, void* d_ws, size_t ws_size,
                              hipStream_t stream)
{
    const float* x      = (const float*)d_in[0];
    const int*   ei     = (const int*)d_in[1];
    const float* w_gcn  = (const float*)d_in[2];
    const float* b_gcn  = (const float*)d_in[3];
    const float* wq     = (const float*)d_in[4];
    const float* bq     = (const float*)d_in[5];
    const float* wk     = (const float*)d_in[6];
    const float* bk     = (const float*)d_in[7];
    const float* wv     = (const float*)d_in[8];
    const float* bv     = (const float*)d_in[9];
    const float* w_skip = (const float*)d_in[10];
    const float* b_skip = (const float*)d_in[11];
    const float* w_beta = (const float*)d_in[12];
    const float* g1     = (const float*)d_in[13];
    const float* b1     = (const float*)d_in[14];
    const float* g2     = (const float*)d_in[15];
    const float* b2     = (const float*)d_in[16];
    const float* w_rel  = (const float*)d_in[17];
    const float* w_root = (const float*)d_in[18];
    const float* lw     = (const float*)d_in[19];
    const float* gw     = (const float*)d_in[20];

    const int N = in_sizes[0] / D;
    const int E = in_sizes[1] / 2;
    const int* src = ei;
    const int* dst = ei + E;

    char* wsb = (char*)d_ws;
    size_t off = 0;
    auto alloc = [&](size_t bytes) -> void* {
        void* p = wsb + off;
        off += (bytes + 255) & ~(size_t)255;
        return p;
    };
    ushort_t* pack_kvx = (ushort_t*)alloc((size_t)N * 384 * 2);  // k|v|xw bf16
    ushort_t* qb_bf    = (ushort_t*)alloc((size_t)N * 128 * 2);
    ushort_t* xbf      = (ushort_t*)alloc((size_t)N * 128 * 2);
    float*    xr       = (float*)alloc((size_t)N * 128 * 4);
    float*    hln      = (float*)alloc((size_t)N * 128 * 4);
    ushort_t* hln_bf   = (ushort_t*)alloc((size_t)N * 128 * 2);
    ushort_t* wt_all   = (ushort_t*)alloc(640 * 128 * 2);
    ushort_t* wt_rel   = (ushort_t*)alloc(256 * 128 * 2);
    ushort_t* wt_root  = (ushort_t*)alloc(128 * 256 * 2);
    float*    bias_all = (float*)alloc(640 * 4);
    int*      deg      = (int*)alloc((size_t)N * 4);
    int*      row_start= (int*)alloc((size_t)(N + 1) * 4);
    int*      cursor   = (int*)alloc((size_t)N * 4);
    int*      csr_src  = (int*)alloc((size_t)E * 4);
    float*    dinv     = (float*)alloc((size_t)N * 4);
    // aliases (dead regions by the time they're written)
    ushort_t* fbuf = pack_kvx;          // [N,256] bf16, written by FFN1 after edge kernel
    float*    out0 = (float*)qb_bf;     // [N,128] f32, spans qb_bf+xbf, written by FFN2

    float* out = (float*)d_out;

    // ---- graph prep ----
    hipMemsetAsync(deg, 0, (size_t)N * sizeof(int), stream);
    deg_count_kernel<<<dim3((E + 255) / 256), dim3(256), 0, stream>>>(dst, deg, E);
    scan_kernel<<<dim3(1), dim3(1024), 0, stream>>>(deg, row_start, cursor, N);
    fill_kernel<<<dim3((E + 255) / 256), dim3(256), 0, stream>>>(src, dst, cursor, csr_src, E);
    dinv_kernel<<<dim3((N + 255) / 256), dim3(256), 0, stream>>>(deg, dinv, N);

    // ---- bf16 conversions ----
    cvt_bf16_kernel<<<dim3((N * 32 + 255) / 256), dim3(256), 0, stream>>>(x, xbf, N * 32);
    pack_weights_kernel<<<dim3(579), dim3(256), 0, stream>>>(
        w_gcn, wq, wk, wv, w_skip, bq, bk, bv, b_skip, w_rel, w_root,
        wt_all, wt_rel, wt_root, bias_all);

    // ---- fused projections: xbf @ [w_gcn|wq|wk|wv|w_skip] ----
    const int MB = (N + 127) / 128;
    gemm_mfma<3><<<dim3(10, MB), dim3(256), 0, stream>>>(
        xbf, wt_all, bias_all, nullptr, N, 128, 640, pack_kvx, qb_bf, xr);

    // ---- fused edge phase ----
    edge_fused_kernel<<<dim3((N + 3) / 4), dim3(256), 0, stream>>>(
        pack_kvx, qb_bf, xr, row_start, csr_src, dinv, b_gcn, w_beta,
        g1, b1, lw, gw, hln, hln_bf, N);

    // ---- FFN ----
    gemm_mfma<2><<<dim3(4, MB), dim3(256), 0, stream>>>(
        hln_bf, wt_rel, nullptr, fbuf, N, 128, 256, nullptr, nullptr, nullptr);
    gemm_mfma<0><<<dim3(2, MB), dim3(256), 0, stream>>>(
        fbuf, wt_root, nullptr, out0, N, 256, 128, nullptr, nullptr, nullptr);

    // ---- final LN ----
    final_ln_kernel<<<dim3((N + 3) / 4), dim3(256), 0, stream>>>(out0, hln, g2, b2, out, N);
}

// Round 3
// 311.797 us; speedup vs baseline: 1.6876x; 1.0155x over previous
//
#include <hip/hip_runtime.h>
#include <math.h>

#define D 128
#define EPSV 1e-5f

typedef unsigned short ushort_t;
typedef __attribute__((ext_vector_type(8))) short short8v;
typedef __attribute__((ext_vector_type(4))) float f32x4;

__device__ __forceinline__ float bf2f(unsigned u) {
    return __uint_as_float(u << 16);
}
__device__ __forceinline__ ushort_t f2bf(float f) {
    unsigned u = __float_as_uint(f);
    unsigned r = (u + 0x7fffu + ((u >> 16) & 1u)) >> 16;   // RNE
    return (ushort_t)r;
}
__device__ __forceinline__ float bfp(uint4 v, int i) {   // bf16 element i of 8
    unsigned w = (&v.x)[i >> 1];
    return bf2f((i & 1) ? (w >> 16) : (w & 0xffffu));
}

// =================== bf16 MFMA GEMM, 128x128 tile ===================
// A: [M,K] bf16 row-major. Bt: [Nout,K] bf16 (transposed weights).
// 4 waves (2Mx2N), each 64x64. K staged in 128-chunks, XOR-swizzled LDS.
// MODE 2 = bf16 out + relu
// MODE 3 = projection epilogue: blockIdx.x picks dest {xw,q,k,v,xr} (all bf16)
// MODE 4 = FFN2 epilogue: out = LayerNorm(acc + hln_bf, g2, b2) -> f32 d_out
template<int MODE>
__global__ __launch_bounds__(256)
void gemm_mfma(const ushort_t* __restrict__ A,
               const ushort_t* __restrict__ Bt,
               const float* __restrict__ bias,
               void* __restrict__ outp, int M, int K, int Nout,
               ushort_t* __restrict__ pack_kvx,
               ushort_t* __restrict__ qb_bf,
               ushort_t* __restrict__ xr_bf,
               const ushort_t* __restrict__ hlnb,
               const float* __restrict__ gg, const float* __restrict__ bb)
{
    __shared__ float smem_f[128 * 132];            // 67.6 KB; aliased below
    ushort_t* As = (ushort_t*)smem_f;              // 128x128 bf16 = 32 KB
    ushort_t* Bs = As + 128 * 128;                 // 128x128 bf16 = 32 KB
    const int tid  = threadIdx.x;
    const int lane = tid & 63, wid = tid >> 6;
    const int wr = wid >> 1, wc = wid & 1;
    const int C0 = blockIdx.x * 128;
    const int R0 = blockIdx.y * 128;

    f32x4 acc[4][4] = {};

    for (int kt = 0; kt < K; kt += 128) {
        #pragma unroll
        for (int it = 0; it < 8; ++it) {            // A tile: 2048 x 16B chunks
            int linear = tid + it * 256;
            int row = linear >> 4, c16 = linear & 15;
            int gr = R0 + row; if (gr >= M) gr = M - 1;
            int sw = c16 ^ (row & 7);
            *reinterpret_cast<short8v*>(&As[row * 128 + sw * 8]) =
                *reinterpret_cast<const short8v*>(&A[(size_t)gr * K + kt + c16 * 8]);
        }
        #pragma unroll
        for (int it = 0; it < 8; ++it) {            // B tile: 2048 x 16B chunks
            int linear = tid + it * 256;
            int row = linear >> 4, c16 = linear & 15;
            int sw = c16 ^ (row & 7);
            *reinterpret_cast<short8v*>(&Bs[row * 128 + sw * 8]) =
                *reinterpret_cast<const short8v*>(&Bt[(size_t)(C0 + row) * K + kt + c16 * 8]);
        }
        __syncthreads();
        #pragma unroll
        for (int ks = 0; ks < 4; ++ks) {
            short8v av[4], bv[4];
            #pragma unroll
            for (int r = 0; r < 4; ++r) {
                int row = wr * 64 + r * 16 + (lane & 15);
                int chunk = (ks * 4 + (lane >> 4)) ^ (row & 7);
                av[r] = *reinterpret_cast<const short8v*>(&As[row * 128 + chunk * 8]);
            }
            #pragma unroll
            for (int c = 0; c < 4; ++c) {
                int row = wc * 64 + c * 16 + (lane & 15);
                int chunk = (ks * 4 + (lane >> 4)) ^ (row & 7);
                bv[c] = *reinterpret_cast<const short8v*>(&Bs[row * 128 + chunk * 8]);
            }
            #pragma unroll
            for (int r = 0; r < 4; ++r)
                #pragma unroll
                for (int c = 0; c < 4; ++c)
                    acc[r][c] = __builtin_amdgcn_mfma_f32_16x16x32_bf16(av[r], bv[c], acc[r][c], 0, 0, 0);
        }
        __syncthreads();
    }

    if (MODE != 4) {
        // D layout: col = lane&15, row = (lane>>4)*4 + i
        const int dest = blockIdx.x;              // MODE 3
        #pragma unroll
        for (int r = 0; r < 4; ++r) {
            int grb = R0 + wr * 64 + r * 16 + (lane >> 4) * 4;
            #pragma unroll
            for (int i = 0; i < 4; ++i) {
                int gr = grb + i;
                if (gr < M) {
                    #pragma unroll
                    for (int c = 0; c < 4; ++c) {
                        int gcl = wc * 64 + c * 16 + (lane & 15);
                        int gc = C0 + gcl;
                        float v = acc[r][c][i];
                        if (bias) v += bias[gc];
                        if (MODE == 2) v = fmaxf(v, 0.f);
                        if (MODE == 2) {
                            ((ushort_t*)outp)[(size_t)gr * Nout + gc] = f2bf(v);
                        } else { // MODE 3
                            if (dest == 0)       pack_kvx[(size_t)gr * 384 + 256 + gcl] = f2bf(v); // xw
                            else if (dest == 1)  qb_bf[(size_t)gr * 128 + gcl] = f2bf(v);          // q
                            else if (dest == 2)  pack_kvx[(size_t)gr * 384 + gcl] = f2bf(v);       // k
                            else if (dest == 3)  pack_kvx[(size_t)gr * 384 + 128 + gcl] = f2bf(v); // v
                            else                 xr_bf[(size_t)gr * 128 + gcl] = f2bf(v);          // skip
                        }
                    }
                }
            }
        }
    } else {
        // FFN2 + residual + LayerNorm2 fused epilogue
        __syncthreads();                           // staging LDS dead, reuse as C
        float* Cs = smem_f;                        // [128][132]
        #pragma unroll
        for (int r = 0; r < 4; ++r) {
            int rowb = wr * 64 + r * 16 + (lane >> 4) * 4;
            #pragma unroll
            for (int i = 0; i < 4; ++i)
                #pragma unroll
                for (int c = 0; c < 4; ++c)
                    Cs[(rowb + i) * 132 + wc * 64 + c * 16 + (lane & 15)] = acc[r][c][i];
        }
        __syncthreads();
        float* outf = (float*)outp;
        const float ga = gg[lane * 2], gb = gg[lane * 2 + 1];
        const float ba = bb[lane * 2], bb2 = bb[lane * 2 + 1];
        for (int rr = 0; rr < 32; ++rr) {
            int row = wid * 32 + rr;
            int gr = R0 + row;
            if (gr >= M) break;
            unsigned hu = *reinterpret_cast<const unsigned*>(&hlnb[(size_t)gr * 128 + lane * 2]);
            float t0 = Cs[row * 132 + lane * 2]     + bf2f(hu & 0xffffu);
            float t1 = Cs[row * 132 + lane * 2 + 1] + bf2f(hu >> 16);
            float ssum = t0 + t1;
            #pragma unroll
            for (int off = 1; off <= 32; off <<= 1) ssum += __shfl_xor(ssum, off);
            float mu = ssum * (1.f / 128.f);
            float dv0 = t0 - mu, dv1 = t1 - mu;
            float vsum = dv0 * dv0 + dv1 * dv1;
            #pragma unroll
            for (int off = 1; off <= 32; off <<= 1) vsum += __shfl_xor(vsum, off);
            float rs = rsqrtf(vsum * (1.f / 128.f) + EPSV);
            float2 o = make_float2(dv0 * rs * ga + ba, dv1 * rs * gb + bb2);
            *reinterpret_cast<float2*>(&outf[(size_t)gr * 128 + lane * 2]) = o;
        }
    }
}

// =================== conversions / packing ===================
__global__ void cvt_bf16_kernel(const float* __restrict__ in, ushort_t* __restrict__ out, int n4)
{
    int i = blockIdx.x * blockDim.x + threadIdx.x;
    if (i < n4) {
        float4 v = reinterpret_cast<const float4*>(in)[i];
        uint2 o;
        o.x = (unsigned)f2bf(v.x) | ((unsigned)f2bf(v.y) << 16);
        o.y = (unsigned)f2bf(v.z) | ((unsigned)f2bf(v.w) << 16);
        reinterpret_cast<uint2*>(out)[i] = o;
    }
}

__global__ void pack_weights_kernel(const float* __restrict__ wg, const float* __restrict__ wq,
                                    const float* __restrict__ wk, const float* __restrict__ wv,
                                    const float* __restrict__ wsk,
                                    const float* __restrict__ bq, const float* __restrict__ bk,
                                    const float* __restrict__ bv, const float* __restrict__ bsk,
                                    const float* __restrict__ wrel, const float* __restrict__ wroot,
                                    ushort_t* __restrict__ wt_all, ushort_t* __restrict__ wt_rel,
                                    ushort_t* __restrict__ wt_root, float* __restrict__ bias_all)
{
    int i = blockIdx.x * 256 + threadIdx.x;
    if (i < 640 * 128) {                         // wt_all[n][k] = W[k][n], 5 concat weights
        int n = i >> 7, k = i & 127;
        const float* srcs[5] = {wg, wq, wk, wv, wsk};
        wt_all[i] = f2bf(srcs[n >> 7][k * 128 + (n & 127)]);
    } else if (i < 640 * 128 + 256 * 128) {      // wt_rel[n][k] = w_rel[k][n]
        int j = i - 640 * 128;
        int n = j >> 7, k = j & 127;
        wt_rel[j] = f2bf(wrel[k * 256 + n]);
    } else if (i < 640 * 128 + 256 * 128 + 128 * 256) {  // wt_root[n][k] = w_root[k][n]
        int j = i - (640 * 128 + 256 * 128);
        int n = j >> 8, k = j & 255;
        wt_root[j] = f2bf(wroot[k * 128 + n]);
    } else if (i < 640 * 128 + 256 * 128 + 128 * 256 + 640) {
        int n = i - (640 * 128 + 256 * 128 + 128 * 256);
        float b = 0.f;                           // cols [0,128) = gcn: bias added later
        if (n >= 128) {
            const float* bs[4] = {bq, bk, bv, bsk};
            b = bs[(n - 128) >> 7][n & 127];
        }
        bias_all[n] = b;
    }
}

// =================== graph prep ===================
__global__ void deg_count_kernel(const int* __restrict__ dst, int* __restrict__ deg, int E)
{
    int e = blockIdx.x * blockDim.x + threadIdx.x;
    if (e < E) atomicAdd(&deg[dst[e]], 1);
}

__global__ __launch_bounds__(1024)
void scan_kernel(const int* __restrict__ deg, int* __restrict__ row_start,
                 int* __restrict__ cursor, int n)
{
    __shared__ int wsum[16];
    const int tid = threadIdx.x, lane = tid & 63, wid = tid >> 6;
    int carry = 0;
    for (int base = 0; base < n; base += 1024) {
        int i = base + tid;
        int v = (i < n) ? deg[i] : 0;
        int xv = v;
        #pragma unroll
        for (int off = 1; off < 64; off <<= 1) {
            int y = __shfl_up(xv, off);
            if (lane >= off) xv += y;
        }
        if (lane == 63) wsum[wid] = xv;
        __syncthreads();
        if (wid == 0) {
            int sv = (lane < 16) ? wsum[lane] : 0;
            #pragma unroll
            for (int off = 1; off < 16; off <<= 1) {
                int y = __shfl_up(sv, off);
                if (lane >= off) sv += y;
            }
            if (lane < 16) wsum[lane] = sv;
        }
        __syncthreads();
        int woff = (wid > 0) ? wsum[wid - 1] : 0;
        int excl = carry + woff + xv - v;
        if (i < n) { row_start[i] = excl; cursor[i] = excl; }
        int total = wsum[15];
        carry += total;
        __syncthreads();
    }
    if (tid == 0) row_start[n] = carry;
}

__global__ void fill_kernel(const int* __restrict__ src, const int* __restrict__ dst,
                            int* __restrict__ cursor, int* __restrict__ csr_src, int E)
{
    int e = blockIdx.x * blockDim.x + threadIdx.x;
    if (e < E) {
        int d = dst[e];
        int pos = atomicAdd(&cursor[d], 1);
        csr_src[pos] = src[e];
    }
}

__global__ void dinv_kernel(const int* __restrict__ deg, float* __restrict__ dinv, int n)
{
    int i = blockIdx.x * blockDim.x + threadIdx.x;
    if (i < n) {
        int d = deg[i];
        dinv[i] = (d > 0) ? rsqrtf((float)d) : 0.f;
    }
}

// ===== fused: GCN gather + attention + beta gate + combine + LayerNorm1 =====
// pack: [N][384] bf16 = k(128) | v(128) | xw(128). 4 edges in parallel per wave:
// slot = lane>>4 (edge), li = lane&15 (8 dims each). No online max (|alpha| << 1).
__global__ __launch_bounds__(256)
void edge_fused_kernel(const ushort_t* __restrict__ pack,
                       const ushort_t* __restrict__ qbf,
                       const ushort_t* __restrict__ xrbf,
                       const int* __restrict__ row_start,
                       const int* __restrict__ csr_src,
                       const float* __restrict__ dinv,
                       const float* __restrict__ b_gcn,
                       const float* __restrict__ w_beta,
                       const float* __restrict__ g1, const float* __restrict__ b1,
                       const float* __restrict__ local_w, const float* __restrict__ global_w,
                       ushort_t* __restrict__ hln_bf, int n)
{
    const int wid = threadIdx.x >> 6, lane = threadIdx.x & 63;
    const int node = blockIdx.x * 4 + wid;
    if (node >= n) return;
    const int slot = lane >> 4, li = lane & 15;
    const int d8 = li * 8;

    uint4 qu = *reinterpret_cast<const uint4*>(&qbf[(size_t)node * 128 + d8]);
    float q[8];
    #pragma unroll
    for (int i = 0; i < 8; ++i) q[i] = bfp(qu, i);

    const int e0 = row_start[node], e1 = row_start[node + 1];
    const float dn = dinv[node];
    const float scale = 0.17677669529663687f;  // 1/sqrt(32)

    float s = 0.f, va[8] = {}, ga[8] = {};

    for (int j = e0; j < e1; j += 4) {
        const int je = j + slot;
        const bool act = je < e1;
        const int sidx = act ? csr_src[je] : 0;
        const ushort_t* prow = pack + (size_t)sidx * 384;
        uint4 ku = *reinterpret_cast<const uint4*>(&prow[d8]);
        uint4 vu = *reinterpret_cast<const uint4*>(&prow[128 + d8]);
        uint4 xu = *reinterpret_cast<const uint4*>(&prow[256 + d8]);
        float p = 0.f;
        #pragma unroll
        for (int i = 0; i < 8; ++i) p = fmaf(q[i], bfp(ku, i), p);
        p += __shfl_xor(p, 1);                   // head = li>>2 : 4-lane groups
        p += __shfl_xor(p, 2);
        float wgt = act ? __expf(p * scale) : 0.f;
        float c   = act ? dn * dinv[sidx] : 0.f;
        s += wgt;
        #pragma unroll
        for (int i = 0; i < 8; ++i) {
            va[i] = fmaf(wgt, bfp(vu, i), va[i]);
            ga[i] = fmaf(c,   bfp(xu, i), ga[i]);
        }
    }
    // combine the 4 slots (butterfly over lane bits 4,5) — all lanes end full
    #pragma unroll
    for (int off = 16; off <= 32; off <<= 1) {
        s += __shfl_xor(s, off);
        #pragma unroll
        for (int i = 0; i < 8; ++i) {
            va[i] += __shfl_xor(va[i], off);
            ga[i] += __shfl_xor(ga[i], off);
        }
    }
    const float denom = fmaxf(s, 1e-16f);        // s is per-head (head = li>>2)

    uint4 xru = *reinterpret_cast<const uint4*>(&xrbf[(size_t)node * 128 + d8]);
    float t[8];
    float part = 0.f;
    #pragma unroll
    for (int i = 0; i < 8; ++i) {
        float og = va[i] / denom;
        float xr = bfp(xru, i);
        float lo = ga[i] + b_gcn[d8 + i];
        part += og * w_beta[d8 + i] + xr * w_beta[128 + d8 + i]
              + (og - xr) * w_beta[256 + d8 + i];
        t[0] = t[0];                              // keep og/xr/lo live via t below
        t[i] = lo;                                // stash lo; og,xr recomputed below
        va[i] = og; ga[i] = xr;                   // reuse regs: va=og, ga=xr
    }
    #pragma unroll
    for (int off = 1; off <= 32; off <<= 1) part += __shfl_xor(part, off);
    const float beta = 1.f / (1.f + __expf(-part * 0.25f));   // 4x duplication

    const float lw = local_w[0], gw = global_w[0];
    float ssum = 0.f;
    #pragma unroll
    for (int i = 0; i < 8; ++i) {
        float go = beta * ga[i] + (1.f - beta) * va[i];
        t[i] = 2.f * (lw * t[i] + gw * go);
        ssum += t[i];
    }
    #pragma unroll
    for (int off = 1; off <= 32; off <<= 1) ssum += __shfl_xor(ssum, off);
    const float mu = ssum * (1.f / 512.f);        // 128 dims x4 duplication
    float vsum = 0.f;
    #pragma unroll
    for (int i = 0; i < 8; ++i) { float d = t[i] - mu; vsum += d * d; }
    #pragma unroll
    for (int off = 1; off <= 32; off <<= 1) vsum += __shfl_xor(vsum, off);
    const float rs = rsqrtf(vsum * (1.f / 512.f) + EPSV);

    if (slot == 0) {
        uint4 o;
        #pragma unroll
        for (int i = 0; i < 4; ++i) {
            float o0 = (t[2*i]   - mu) * rs * g1[d8 + 2*i]   + b1[d8 + 2*i];
            float o1 = (t[2*i+1] - mu) * rs * g1[d8 + 2*i+1] + b1[d8 + 2*i+1];
            (&o.x)[i] = (unsigned)f2bf(o0) | ((unsigned)f2bf(o1) << 16);
        }
        *reinterpret_cast<uint4*>(&hln_bf[(size_t)node * 128 + d8]) = o;
    }
}

// =================== launch ===================
extern "C" void kernel_launch(void* const* d_in, const int* in_sizes, int n_in,
                              void* d_out, int out_size, void* d_ws, size_t ws_size,
                              hipStream_t stream)
{
    const float* x      = (const float*)d_in[0];
    const int*   ei     = (const int*)d_in[1];
    const float* w_gcn  = (const float*)d_in[2];
    const float* b_gcn  = (const float*)d_in[3];
    const float* wq     = (const float*)d_in[4];
    const float* bq     = (const float*)d_in[5];
    const float* wk     = (const float*)d_in[6];
    const float* bk     = (const float*)d_in[7];
    const float* wv     = (const float*)d_in[8];
    const float* bv     = (const float*)d_in[9];
    const float* w_skip = (const float*)d_in[10];
    const float* b_skip = (const float*)d_in[11];
    const float* w_beta = (const float*)d_in[12];
    const float* g1     = (const float*)d_in[13];
    const float* b1     = (const float*)d_in[14];
    const float* g2     = (const float*)d_in[15];
    const float* b2     = (const float*)d_in[16];
    const float* w_rel  = (const float*)d_in[17];
    const float* w_root = (const float*)d_in[18];
    const float* lw     = (const float*)d_in[19];
    const float* gw     = (const float*)d_in[20];

    const int N = in_sizes[0] / D;
    const int E = in_sizes[1] / 2;
    const int* src = ei;
    const int* dst = ei + E;

    char* wsb = (char*)d_ws;
    size_t off = 0;
    auto alloc = [&](size_t bytes) -> void* {
        void* p = wsb + off;
        off += (bytes + 255) & ~(size_t)255;
        return p;
    };
    ushort_t* pack_kvx = (ushort_t*)alloc((size_t)N * 384 * 2);  // k|v|xw bf16
    ushort_t* qb_bf    = (ushort_t*)alloc((size_t)N * 128 * 2);
    ushort_t* xbf      = (ushort_t*)alloc((size_t)N * 128 * 2);
    ushort_t* xr_bf    = (ushort_t*)alloc((size_t)N * 128 * 2);
    ushort_t* hln_bf   = (ushort_t*)alloc((size_t)N * 128 * 2);
    ushort_t* wt_all   = (ushort_t*)alloc(640 * 128 * 2);
    ushort_t* wt_rel   = (ushort_t*)alloc(256 * 128 * 2);
    ushort_t* wt_root  = (ushort_t*)alloc(128 * 256 * 2);
    float*    bias_all = (float*)alloc(640 * 4);
    int*      deg      = (int*)alloc((size_t)N * 4);
    int*      row_start= (int*)alloc((size_t)(N + 1) * 4);
    int*      cursor   = (int*)alloc((size_t)N * 4);
    int*      csr_src  = (int*)alloc((size_t)E * 4);
    float*    dinv     = (float*)alloc((size_t)N * 4);
    ushort_t* fbuf = pack_kvx;          // [N,256] bf16 alias (pack dead by FFN time)

    float* out = (float*)d_out;

    // ---- graph prep ----
    hipMemsetAsync(deg, 0, (size_t)N * sizeof(int), stream);
    deg_count_kernel<<<dim3((E + 255) / 256), dim3(256), 0, stream>>>(dst, deg, E);
    scan_kernel<<<dim3(1), dim3(1024), 0, stream>>>(deg, row_start, cursor, N);
    fill_kernel<<<dim3((E + 255) / 256), dim3(256), 0, stream>>>(src, dst, cursor, csr_src, E);
    dinv_kernel<<<dim3((N + 255) / 256), dim3(256), 0, stream>>>(deg, dinv, N);

    // ---- bf16 conversions ----
    cvt_bf16_kernel<<<dim3((N * 32 + 255) / 256), dim3(256), 0, stream>>>(x, xbf, N * 32);
    pack_weights_kernel<<<dim3(579), dim3(256), 0, stream>>>(
        w_gcn, wq, wk, wv, w_skip, bq, bk, bv, b_skip, w_rel, w_root,
        wt_all, wt_rel, wt_root, bias_all);

    // ---- fused projections: xbf @ [w_gcn|wq|wk|wv|w_skip] ----
    const int MB = (N + 127) / 128;
    gemm_mfma<3><<<dim3(5, MB), dim3(256), 0, stream>>>(
        xbf, wt_all, bias_all, nullptr, N, 128, 640,
        pack_kvx, qb_bf, xr_bf, nullptr, nullptr, nullptr);

    // ---- fused edge phase ----
    edge_fused_kernel<<<dim3((N + 3) / 4), dim3(256), 0, stream>>>(
        pack_kvx, qb_bf, xr_bf, row_start, csr_src, dinv, b_gcn, w_beta,
        g1, b1, lw, gw, hln_bf, N);

    // ---- FFN1 (relu, bf16) ----
    gemm_mfma<2><<<dim3(2, MB), dim3(256), 0, stream>>>(
        hln_bf, wt_rel, nullptr, fbuf, N, 128, 256,
        nullptr, nullptr, nullptr, nullptr, nullptr, nullptr);
    // ---- FFN2 + residual + LN2 -> out ----
    gemm_mfma<4><<<dim3(1, MB), dim3(256), 0, stream>>>(
        fbuf, wt_root, nullptr, out, N, 256, 128,
        nullptr, nullptr, nullptr, hln_bf, g2, b2);
}

// Round 4
// 293.069 us; speedup vs baseline: 1.7954x; 1.0639x over previous
//
#include <hip/hip_runtime.h>
#include <math.h>

#define D 128
#define EPSV 1e-5f

typedef unsigned short ushort_t;
typedef __attribute__((ext_vector_type(8))) short short8v;
typedef __attribute__((ext_vector_type(4))) float f32x4;

__device__ __forceinline__ float bf2f(unsigned u) {
    return __uint_as_float(u << 16);
}
__device__ __forceinline__ ushort_t f2bf(float f) {
    unsigned u = __float_as_uint(f);
    unsigned r = (u + 0x7fffu + ((u >> 16) & 1u)) >> 16;   // RNE
    return (ushort_t)r;
}
__device__ __forceinline__ float bfp(uint4 v, int i) {   // bf16 element i of 8
    unsigned w = (&v.x)[i >> 1];
    return bf2f((i & 1) ? (w >> 16) : (w & 0xffffu));
}

// ============ projection GEMM: pack/q/xr = x @ [w_gcn|wq|wk|wv|w_skip] ============
// No LDS staging: A,B MFMA fragments loaded directly from global (B is L2-resident,
// A is L3-resident). A fragments (K=128) held in registers across all 5 col-tiles.
// LDS only as bf16 epilogue buffer -> 16B coalesced stores.
__global__ __launch_bounds__(256)
void proj_gemm(const float* __restrict__ x,
               const ushort_t* __restrict__ Bt,   // wt_all [640][128]
               const float* __restrict__ bias,    // [640]
               ushort_t* __restrict__ pack, ushort_t* __restrict__ qb,
               ushort_t* __restrict__ xrb, int M)
{
    __shared__ ushort_t Cs[128 * 136];
    const int tid = threadIdx.x, lane = tid & 63, wid = tid >> 6;
    const int wr = wid >> 1, wc = wid & 1;
    const int R0 = blockIdx.x * 128;

    short8v av[4][4];                         // [r][ks], bf16 converted from f32 x
    #pragma unroll
    for (int r = 0; r < 4; ++r) {
        int gr = R0 + wr * 64 + r * 16 + (lane & 15);
        if (gr >= M) gr = M - 1;
        const float* xrow = x + (size_t)gr * 128 + (lane >> 4) * 8;
        #pragma unroll
        for (int ks = 0; ks < 4; ++ks) {
            float4 lo = *reinterpret_cast<const float4*>(xrow + ks * 32);
            float4 hi = *reinterpret_cast<const float4*>(xrow + ks * 32 + 4);
            short8v a;
            a[0] = (short)f2bf(lo.x); a[1] = (short)f2bf(lo.y);
            a[2] = (short)f2bf(lo.z); a[3] = (short)f2bf(lo.w);
            a[4] = (short)f2bf(hi.x); a[5] = (short)f2bf(hi.y);
            a[6] = (short)f2bf(hi.z); a[7] = (short)f2bf(hi.w);
            av[r][ks] = a;
        }
    }

    for (int ct = 0; ct < 5; ++ct) {
        f32x4 acc[4][4] = {};
        #pragma unroll
        for (int ks = 0; ks < 4; ++ks) {
            short8v bv[4];
            #pragma unroll
            for (int c = 0; c < 4; ++c) {
                int col = ct * 128 + wc * 64 + c * 16 + (lane & 15);
                bv[c] = *reinterpret_cast<const short8v*>(
                    &Bt[(size_t)col * 128 + ks * 32 + (lane >> 4) * 8]);
            }
            #pragma unroll
            for (int r = 0; r < 4; ++r)
                #pragma unroll
                for (int c = 0; c < 4; ++c)
                    acc[r][c] = __builtin_amdgcn_mfma_f32_16x16x32_bf16(av[r][ks], bv[c], acc[r][c], 0, 0, 0);
        }
        __syncthreads();                      // Cs free from previous ct
        #pragma unroll
        for (int r = 0; r < 4; ++r) {
            int rowb = wr * 64 + r * 16 + (lane >> 4) * 4;
            #pragma unroll
            for (int i = 0; i < 4; ++i)
                #pragma unroll
                for (int c = 0; c < 4; ++c) {
                    int col = wc * 64 + c * 16 + (lane & 15);
                    Cs[(rowb + i) * 136 + col] = f2bf(acc[r][c][i] + bias[ct * 128 + col]);
                }
        }
        __syncthreads();
        #pragma unroll
        for (int it = 0; it < 8; ++it) {      // 128 rows x 16 chunks of 16B
            int linear = tid + it * 256;
            int row = linear >> 4, ch = linear & 15;
            int gr = R0 + row;
            if (gr < M) {
                uint4 v = *reinterpret_cast<const uint4*>(&Cs[row * 136 + ch * 8]);
                ushort_t* dst;
                if (ct == 0)      dst = pack + (size_t)gr * 384 + 256;  // xw
                else if (ct == 1) dst = qb   + (size_t)gr * 128;        // q
                else if (ct == 2) dst = pack + (size_t)gr * 384;        // k
                else if (ct == 3) dst = pack + (size_t)gr * 384 + 128;  // v
                else              dst = xrb  + (size_t)gr * 128;        // x_r
                *reinterpret_cast<uint4*>(dst + ch * 8) = v;
            }
        }
    }
}

// ============ FFN1: fbuf = relu(hln @ w_rel), bf16 in/out ============
__global__ __launch_bounds__(256)
void ffn1_gemm(const ushort_t* __restrict__ A,    // hln_bf [M][128]
               const ushort_t* __restrict__ Bt,   // wt_rel [256][128]
               ushort_t* __restrict__ outb,       // fbuf [M][256]
               int M)
{
    __shared__ ushort_t Cs[128 * 136];
    const int tid = threadIdx.x, lane = tid & 63, wid = tid >> 6;
    const int wr = wid >> 1, wc = wid & 1;
    const int R0 = blockIdx.x * 128;

    short8v av[4][4];
    #pragma unroll
    for (int r = 0; r < 4; ++r) {
        int gr = R0 + wr * 64 + r * 16 + (lane & 15);
        if (gr >= M) gr = M - 1;
        #pragma unroll
        for (int ks = 0; ks < 4; ++ks)
            av[r][ks] = *reinterpret_cast<const short8v*>(
                &A[(size_t)gr * 128 + ks * 32 + (lane >> 4) * 8]);
    }

    for (int ct = 0; ct < 2; ++ct) {
        f32x4 acc[4][4] = {};
        #pragma unroll
        for (int ks = 0; ks < 4; ++ks) {
            short8v bv[4];
            #pragma unroll
            for (int c = 0; c < 4; ++c) {
                int col = ct * 128 + wc * 64 + c * 16 + (lane & 15);
                bv[c] = *reinterpret_cast<const short8v*>(
                    &Bt[(size_t)col * 128 + ks * 32 + (lane >> 4) * 8]);
            }
            #pragma unroll
            for (int r = 0; r < 4; ++r)
                #pragma unroll
                for (int c = 0; c < 4; ++c)
                    acc[r][c] = __builtin_amdgcn_mfma_f32_16x16x32_bf16(av[r][ks], bv[c], acc[r][c], 0, 0, 0);
        }
        __syncthreads();
        #pragma unroll
        for (int r = 0; r < 4; ++r) {
            int rowb = wr * 64 + r * 16 + (lane >> 4) * 4;
            #pragma unroll
            for (int i = 0; i < 4; ++i)
                #pragma unroll
                for (int c = 0; c < 4; ++c) {
                    int col = wc * 64 + c * 16 + (lane & 15);
                    Cs[(rowb + i) * 136 + col] = f2bf(fmaxf(acc[r][c][i], 0.f));
                }
        }
        __syncthreads();
        #pragma unroll
        for (int it = 0; it < 8; ++it) {
            int linear = tid + it * 256;
            int row = linear >> 4, ch = linear & 15;
            int gr = R0 + row;
            if (gr < M)
                *reinterpret_cast<uint4*>(&outb[(size_t)gr * 256 + ct * 128 + ch * 8]) =
                    *reinterpret_cast<const uint4*>(&Cs[row * 136 + ch * 8]);
        }
    }
}

// ============ FFN2 + residual + LayerNorm2 -> f32 out ============
__global__ __launch_bounds__(256)
void ffn2_ln_gemm(const ushort_t* __restrict__ A,   // fbuf [M][256]
                  const ushort_t* __restrict__ Bt,  // wt_root [128][256]
                  const ushort_t* __restrict__ hlnb,
                  const float* __restrict__ g2, const float* __restrict__ b2,
                  float* __restrict__ outf, int M)
{
    __shared__ float Cs[128 * 132];
    const int tid = threadIdx.x, lane = tid & 63, wid = tid >> 6;
    const int wr = wid >> 1, wc = wid & 1;
    const int R0 = blockIdx.x * 128;

    f32x4 acc[4][4] = {};
    #pragma unroll
    for (int ks = 0; ks < 8; ++ks) {
        short8v ar[4], bv[4];
        #pragma unroll
        for (int r = 0; r < 4; ++r) {
            int gr = R0 + wr * 64 + r * 16 + (lane & 15);
            if (gr >= M) gr = M - 1;
            ar[r] = *reinterpret_cast<const short8v*>(
                &A[(size_t)gr * 256 + ks * 32 + (lane >> 4) * 8]);
        }
        #pragma unroll
        for (int c = 0; c < 4; ++c) {
            int col = wc * 64 + c * 16 + (lane & 15);
            bv[c] = *reinterpret_cast<const short8v*>(
                &Bt[(size_t)col * 256 + ks * 32 + (lane >> 4) * 8]);
        }
        #pragma unroll
        for (int r = 0; r < 4; ++r)
            #pragma unroll
            for (int c = 0; c < 4; ++c)
                acc[r][c] = __builtin_amdgcn_mfma_f32_16x16x32_bf16(ar[r], bv[c], acc[r][c], 0, 0, 0);
    }

    #pragma unroll
    for (int r = 0; r < 4; ++r) {
        int rowb = wr * 64 + r * 16 + (lane >> 4) * 4;
        #pragma unroll
        for (int i = 0; i < 4; ++i)
            #pragma unroll
            for (int c = 0; c < 4; ++c)
                Cs[(rowb + i) * 132 + wc * 64 + c * 16 + (lane & 15)] = acc[r][c][i];
    }
    __syncthreads();

    const float ga = g2[lane * 2], gb = g2[lane * 2 + 1];
    const float ba = b2[lane * 2], bb2 = b2[lane * 2 + 1];
    for (int rr = 0; rr < 32; ++rr) {
        int row = wid * 32 + rr;
        int gr = R0 + row;
        if (gr >= M) break;
        unsigned hu = *reinterpret_cast<const unsigned*>(&hlnb[(size_t)gr * 128 + lane * 2]);
        float t0 = Cs[row * 132 + lane * 2]     + bf2f(hu & 0xffffu);
        float t1 = Cs[row * 132 + lane * 2 + 1] + bf2f(hu >> 16);
        float ssum = t0 + t1;
        #pragma unroll
        for (int off = 1; off <= 32; off <<= 1) ssum += __shfl_xor(ssum, off);
        float mu = ssum * (1.f / 128.f);
        float dv0 = t0 - mu, dv1 = t1 - mu;
        float vsum = dv0 * dv0 + dv1 * dv1;
        #pragma unroll
        for (int off = 1; off <= 32; off <<= 1) vsum += __shfl_xor(vsum, off);
        float rs = rsqrtf(vsum * (1.f / 128.f) + EPSV);
        float2 o = make_float2(dv0 * rs * ga + ba, dv1 * rs * gb + bb2);
        *reinterpret_cast<float2*>(&outf[(size_t)gr * 128 + lane * 2]) = o;
    }
}

// =================== weight packing ===================
__global__ void pack_weights_kernel(const float* __restrict__ wg, const float* __restrict__ wq,
                                    const float* __restrict__ wk, const float* __restrict__ wv,
                                    const float* __restrict__ wsk,
                                    const float* __restrict__ bq, const float* __restrict__ bk,
                                    const float* __restrict__ bv, const float* __restrict__ bsk,
                                    const float* __restrict__ wrel, const float* __restrict__ wroot,
                                    ushort_t* __restrict__ wt_all, ushort_t* __restrict__ wt_rel,
                                    ushort_t* __restrict__ wt_root, float* __restrict__ bias_all)
{
    int i = blockIdx.x * 256 + threadIdx.x;
    if (i < 640 * 128) {                         // wt_all[n][k] = W[k][n], 5 concat weights
        int n = i >> 7, k = i & 127;
        const float* srcs[5] = {wg, wq, wk, wv, wsk};
        wt_all[i] = f2bf(srcs[n >> 7][k * 128 + (n & 127)]);
    } else if (i < 640 * 128 + 256 * 128) {      // wt_rel[n][k] = w_rel[k][n]
        int j = i - 640 * 128;
        int n = j >> 7, k = j & 127;
        wt_rel[j] = f2bf(wrel[k * 256 + n]);
    } else if (i < 640 * 128 + 256 * 128 + 128 * 256) {  // wt_root[n][k] = w_root[k][n]
        int j = i - (640 * 128 + 256 * 128);
        int n = j >> 8, k = j & 255;
        wt_root[j] = f2bf(wroot[k * 128 + n]);
    } else if (i < 640 * 128 + 256 * 128 + 128 * 256 + 640) {
        int n = i - (640 * 128 + 256 * 128 + 128 * 256);
        float b = 0.f;                           // cols [0,128) = gcn: bias added in edge kernel
        if (n >= 128) {
            const float* bs[4] = {bq, bk, bv, bsk};
            b = bs[(n - 128) >> 7][n & 127];
        }
        bias_all[n] = b;
    }
}

// =================== graph prep ===================
__global__ void deg_count_kernel(const int* __restrict__ dst, int* __restrict__ deg, int E)
{
    int e = blockIdx.x * blockDim.x + threadIdx.x;
    if (e < E) atomicAdd(&deg[dst[e]], 1);
}

__global__ __launch_bounds__(1024)
void scan_kernel(const int* __restrict__ deg, int* __restrict__ row_start,
                 int* __restrict__ cursor, int n)
{
    __shared__ int wsum[16];
    const int tid = threadIdx.x, lane = tid & 63, wid = tid >> 6;
    int carry = 0;
    for (int base = 0; base < n; base += 1024) {
        int i = base + tid;
        int v = (i < n) ? deg[i] : 0;
        int xv = v;
        #pragma unroll
        for (int off = 1; off < 64; off <<= 1) {
            int y = __shfl_up(xv, off);
            if (lane >= off) xv += y;
        }
        if (lane == 63) wsum[wid] = xv;
        __syncthreads();
        if (wid == 0) {
            int sv = (lane < 16) ? wsum[lane] : 0;
            #pragma unroll
            for (int off = 1; off < 16; off <<= 1) {
                int y = __shfl_up(sv, off);
                if (lane >= off) sv += y;
            }
            if (lane < 16) wsum[lane] = sv;
        }
        __syncthreads();
        int woff = (wid > 0) ? wsum[wid - 1] : 0;
        int excl = carry + woff + xv - v;
        if (i < n) { row_start[i] = excl; cursor[i] = excl; }
        int total = wsum[15];
        carry += total;
        __syncthreads();
    }
    if (tid == 0) row_start[n] = carry;
}

__global__ void fill_kernel(const int* __restrict__ src, const int* __restrict__ dst,
                            int* __restrict__ cursor, int* __restrict__ csr_src, int E)
{
    int e = blockIdx.x * blockDim.x + threadIdx.x;
    if (e < E) {
        int d = dst[e];
        int pos = atomicAdd(&cursor[d], 1);
        csr_src[pos] = src[e];
    }
}

__global__ void dinv_kernel(const int* __restrict__ deg, float* __restrict__ dinv, int n)
{
    int i = blockIdx.x * blockDim.x + threadIdx.x;
    if (i < n) {
        int d = deg[i];
        dinv[i] = (d > 0) ? rsqrtf((float)d) : 0.f;
    }
}

// ===== fused: GCN gather + attention + beta gate + combine + LayerNorm1 =====
// pack: [N][384] bf16 = k(128) | v(128) | xw(128). 4 edges in parallel per wave:
// slot = lane>>4 (edge), li = lane&15 (8 dims each). No online max (|alpha| << 1).
__global__ __launch_bounds__(256)
void edge_fused_kernel(const ushort_t* __restrict__ pack,
                       const ushort_t* __restrict__ qbf,
                       const ushort_t* __restrict__ xrbf,
                       const int* __restrict__ row_start,
                       const int* __restrict__ csr_src,
                       const float* __restrict__ dinv,
                       const float* __restrict__ b_gcn,
                       const float* __restrict__ w_beta,
                       const float* __restrict__ g1, const float* __restrict__ b1,
                       const float* __restrict__ local_w, const float* __restrict__ global_w,
                       ushort_t* __restrict__ hln_bf, int n)
{
    const int wid = threadIdx.x >> 6, lane = threadIdx.x & 63;
    const int node = blockIdx.x * 4 + wid;
    if (node >= n) return;
    const int slot = lane >> 4, li = lane & 15;
    const int d8 = li * 8;

    uint4 qu = *reinterpret_cast<const uint4*>(&qbf[(size_t)node * 128 + d8]);
    float q[8];
    #pragma unroll
    for (int i = 0; i < 8; ++i) q[i] = bfp(qu, i);

    const int e0 = row_start[node], e1 = row_start[node + 1];
    const float dn = dinv[node];
    const float scale = 0.17677669529663687f;  // 1/sqrt(32)

    float s = 0.f, va[8] = {}, ga[8] = {};

    for (int j = e0; j < e1; j += 4) {
        const int je = j + slot;
        const bool act = je < e1;
        const int sidx = act ? csr_src[je] : 0;
        const ushort_t* prow = pack + (size_t)sidx * 384;
        uint4 ku = *reinterpret_cast<const uint4*>(&prow[d8]);
        uint4 vu = *reinterpret_cast<const uint4*>(&prow[128 + d8]);
        uint4 xu = *reinterpret_cast<const uint4*>(&prow[256 + d8]);
        float p = 0.f;
        #pragma unroll
        for (int i = 0; i < 8; ++i) p = fmaf(q[i], bfp(ku, i), p);
        p += __shfl_xor(p, 1);                   // head = li>>2 : 4-lane groups
        p += __shfl_xor(p, 2);
        float wgt = act ? __expf(p * scale) : 0.f;
        float c   = act ? dn * dinv[sidx] : 0.f;
        s += wgt;
        #pragma unroll
        for (int i = 0; i < 8; ++i) {
            va[i] = fmaf(wgt, bfp(vu, i), va[i]);
            ga[i] = fmaf(c,   bfp(xu, i), ga[i]);
        }
    }
    // combine the 4 slots (butterfly over lane bits 4,5)
    #pragma unroll
    for (int off = 16; off <= 32; off <<= 1) {
        s += __shfl_xor(s, off);
        #pragma unroll
        for (int i = 0; i < 8; ++i) {
            va[i] += __shfl_xor(va[i], off);
            ga[i] += __shfl_xor(ga[i], off);
        }
    }
    const float denom = fmaxf(s, 1e-16f);        // per-head (head = li>>2)

    uint4 xru = *reinterpret_cast<const uint4*>(&xrbf[(size_t)node * 128 + d8]);
    float t[8];
    float part = 0.f;
    #pragma unroll
    for (int i = 0; i < 8; ++i) {
        float og = va[i] / denom;
        float xr = bfp(xru, i);
        float lo = ga[i] + b_gcn[d8 + i];
        part += og * w_beta[d8 + i] + xr * w_beta[128 + d8 + i]
              + (og - xr) * w_beta[256 + d8 + i];
        t[i] = lo;
        va[i] = og; ga[i] = xr;                   // reuse regs: va=og, ga=xr
    }
    #pragma unroll
    for (int off = 1; off <= 32; off <<= 1) part += __shfl_xor(part, off);
    const float beta = 1.f / (1.f + __expf(-part * 0.25f));   // 4x duplication

    const float lw = local_w[0], gw = global_w[0];
    float ssum = 0.f;
    #pragma unroll
    for (int i = 0; i < 8; ++i) {
        float go = beta * ga[i] + (1.f - beta) * va[i];
        t[i] = 2.f * (lw * t[i] + gw * go);
        ssum += t[i];
    }
    #pragma unroll
    for (int off = 1; off <= 32; off <<= 1) ssum += __shfl_xor(ssum, off);
    const float mu = ssum * (1.f / 512.f);        // 128 dims x4 duplication
    float vsum = 0.f;
    #pragma unroll
    for (int i = 0; i < 8; ++i) { float d = t[i] - mu; vsum += d * d; }
    #pragma unroll
    for (int off = 1; off <= 32; off <<= 1) vsum += __shfl_xor(vsum, off);
    const float rs = rsqrtf(vsum * (1.f / 512.f) + EPSV);

    if (slot == 0) {
        uint4 o;
        #pragma unroll
        for (int i = 0; i < 4; ++i) {
            float o0 = (t[2*i]   - mu) * rs * g1[d8 + 2*i]   + b1[d8 + 2*i];
            float o1 = (t[2*i+1] - mu) * rs * g1[d8 + 2*i+1] + b1[d8 + 2*i+1];
            (&o.x)[i] = (unsigned)f2bf(o0) | ((unsigned)f2bf(o1) << 16);
        }
        *reinterpret_cast<uint4*>(&hln_bf[(size_t)node * 128 + d8]) = o;
    }
}

// =================== launch ===================
extern "C" void kernel_launch(void* const* d_in, const int* in_sizes, int n_in,
                              void* d_out, int out_size, void* d_ws, size_t ws_size,
                              hipStream_t stream)
{
    const float* x      = (const float*)d_in[0];
    const int*   ei     = (const int*)d_in[1];
    const float* w_gcn  = (const float*)d_in[2];
    const float* b_gcn  = (const float*)d_in[3];
    const float* wq     = (const float*)d_in[4];
    const float* bq     = (const float*)d_in[5];
    const float* wk     = (const float*)d_in[6];
    const float* bk     = (const float*)d_in[7];
    const float* wv     = (const float*)d_in[8];
    const float* bv     = (const float*)d_in[9];
    const float* w_skip = (const float*)d_in[10];
    const float* b_skip = (const float*)d_in[11];
    const float* w_beta = (const float*)d_in[12];
    const float* g1     = (const float*)d_in[13];
    const float* b1     = (const float*)d_in[14];
    const float* g2     = (const float*)d_in[15];
    const float* b2     = (const float*)d_in[16];
    const float* w_rel  = (const float*)d_in[17];
    const float* w_root = (const float*)d_in[18];
    const float* lw     = (const float*)d_in[19];
    const float* gw     = (const float*)d_in[20];

    const int N = in_sizes[0] / D;
    const int E = in_sizes[1] / 2;
    const int* src = ei;
    const int* dst = ei + E;

    char* wsb = (char*)d_ws;
    size_t off = 0;
    auto alloc = [&](size_t bytes) -> void* {
        void* p = wsb + off;
        off += (bytes + 255) & ~(size_t)255;
        return p;
    };
    ushort_t* pack_kvx = (ushort_t*)alloc((size_t)N * 384 * 2);  // k|v|xw bf16
    ushort_t* qb_bf    = (ushort_t*)alloc((size_t)N * 128 * 2);
    ushort_t* xr_bf    = (ushort_t*)alloc((size_t)N * 128 * 2);
    ushort_t* hln_bf   = (ushort_t*)alloc((size_t)N * 128 * 2);
    ushort_t* wt_all   = (ushort_t*)alloc(640 * 128 * 2);
    ushort_t* wt_rel   = (ushort_t*)alloc(256 * 128 * 2);
    ushort_t* wt_root  = (ushort_t*)alloc(128 * 256 * 2);
    float*    bias_all = (float*)alloc(640 * 4);
    int*      deg      = (int*)alloc((size_t)N * 4);
    int*      row_start= (int*)alloc((size_t)(N + 1) * 4);
    int*      cursor   = (int*)alloc((size_t)N * 4);
    int*      csr_src  = (int*)alloc((size_t)E * 4);
    float*    dinv     = (float*)alloc((size_t)N * 4);
    ushort_t* fbuf = pack_kvx;          // [N,256] bf16 alias (pack dead by FFN time)

    float* out = (float*)d_out;

    // ---- graph prep ----
    hipMemsetAsync(deg, 0, (size_t)N * sizeof(int), stream);
    deg_count_kernel<<<dim3((E + 255) / 256), dim3(256), 0, stream>>>(dst, deg, E);
    scan_kernel<<<dim3(1), dim3(1024), 0, stream>>>(deg, row_start, cursor, N);
    fill_kernel<<<dim3((E + 255) / 256), dim3(256), 0, stream>>>(src, dst, cursor, csr_src, E);
    dinv_kernel<<<dim3((N + 255) / 256), dim3(256), 0, stream>>>(deg, dinv, N);

    // ---- weights ----
    pack_weights_kernel<<<dim3(579), dim3(256), 0, stream>>>(
        w_gcn, wq, wk, wv, w_skip, bq, bk, bv, b_skip, w_rel, w_root,
        wt_all, wt_rel, wt_root, bias_all);

    // ---- fused projections (reads f32 x directly) ----
    const int MB = (N + 127) / 128;
    proj_gemm<<<dim3(MB), dim3(256), 0, stream>>>(
        x, wt_all, bias_all, pack_kvx, qb_bf, xr_bf, N);

    // ---- fused edge phase ----
    edge_fused_kernel<<<dim3((N + 3) / 4), dim3(256), 0, stream>>>(
        pack_kvx, qb_bf, xr_bf, row_start, csr_src, dinv, b_gcn, w_beta,
        g1, b1, lw, gw, hln_bf, N);

    // ---- FFN ----
    ffn1_gemm<<<dim3(MB), dim3(256), 0, stream>>>(hln_bf, wt_rel, fbuf, N);
    ffn2_ln_gemm<<<dim3(MB), dim3(256), 0, stream>>>(fbuf, wt_root, hln_bf, g2, b2, out, N);
}

// Round 5
// 234.277 us; speedup vs baseline: 2.2460x; 1.2510x over previous
//
#include <hip/hip_runtime.h>
#include <math.h>

#define D 128
#define EPSV 1e-5f

typedef unsigned short ushort_t;
typedef __attribute__((ext_vector_type(8))) short short8v;
typedef __attribute__((ext_vector_type(4))) float f32x4;

__device__ __forceinline__ float bf2f(unsigned u) {
    return __uint_as_float(u << 16);
}
__device__ __forceinline__ ushort_t f2bf(float f) {
    unsigned u = __float_as_uint(f);
    unsigned r = (u + 0x7fffu + ((u >> 16) & 1u)) >> 16;   // RNE
    return (ushort_t)r;
}
__device__ __forceinline__ float bfp(uint4 v, int i) {   // bf16 element i of 8
    unsigned w = (&v.x)[i >> 1];
    return bf2f((i & 1) ? (w >> 16) : (w & 0xffffu));
}

// ============ projection GEMM: pack/q/xr = x @ [w_gcn|wq|wk|wv|w_skip] ============
// grid (MB, 2): blockIdx.y splits col-tiles {0,1,2} / {3,4} for 2x parallelism.
// A fragments loaded once (f32 -> bf16), B direct from global (L2-hot).
__global__ __launch_bounds__(256)
void proj_gemm(const float* __restrict__ x,
               const ushort_t* __restrict__ Bt,   // wt_all [640][128]
               const float* __restrict__ bias,    // [640]
               ushort_t* __restrict__ pack, ushort_t* __restrict__ qb,
               ushort_t* __restrict__ xrb, int M)
{
    __shared__ ushort_t Cs[128 * 136];
    const int tid = threadIdx.x, lane = tid & 63, wid = tid >> 6;
    const int wr = wid >> 1, wc = wid & 1;
    const int R0 = blockIdx.x * 128;
    const int cbeg = blockIdx.y ? 3 : 0;
    const int cend = blockIdx.y ? 5 : 3;

    short8v av[4][4];                         // [r][ks], bf16 converted from f32 x
    #pragma unroll
    for (int r = 0; r < 4; ++r) {
        int gr = R0 + wr * 64 + r * 16 + (lane & 15);
        if (gr >= M) gr = M - 1;
        const float* xrow = x + (size_t)gr * 128 + (lane >> 4) * 8;
        #pragma unroll
        for (int ks = 0; ks < 4; ++ks) {
            float4 lo = *reinterpret_cast<const float4*>(xrow + ks * 32);
            float4 hi = *reinterpret_cast<const float4*>(xrow + ks * 32 + 4);
            short8v a;
            a[0] = (short)f2bf(lo.x); a[1] = (short)f2bf(lo.y);
            a[2] = (short)f2bf(lo.z); a[3] = (short)f2bf(lo.w);
            a[4] = (short)f2bf(hi.x); a[5] = (short)f2bf(hi.y);
            a[6] = (short)f2bf(hi.z); a[7] = (short)f2bf(hi.w);
            av[r][ks] = a;
        }
    }

    for (int ct = cbeg; ct < cend; ++ct) {
        f32x4 acc[4][4] = {};
        #pragma unroll
        for (int ks = 0; ks < 4; ++ks) {
            short8v bv[4];
            #pragma unroll
            for (int c = 0; c < 4; ++c) {
                int col = ct * 128 + wc * 64 + c * 16 + (lane & 15);
                bv[c] = *reinterpret_cast<const short8v*>(
                    &Bt[(size_t)col * 128 + ks * 32 + (lane >> 4) * 8]);
            }
            #pragma unroll
            for (int r = 0; r < 4; ++r)
                #pragma unroll
                for (int c = 0; c < 4; ++c)
                    acc[r][c] = __builtin_amdgcn_mfma_f32_16x16x32_bf16(av[r][ks], bv[c], acc[r][c], 0, 0, 0);
        }
        __syncthreads();                      // Cs free from previous ct
        #pragma unroll
        for (int r = 0; r < 4; ++r) {
            int rowb = wr * 64 + r * 16 + (lane >> 4) * 4;
            #pragma unroll
            for (int i = 0; i < 4; ++i)
                #pragma unroll
                for (int c = 0; c < 4; ++c) {
                    int col = wc * 64 + c * 16 + (lane & 15);
                    Cs[(rowb + i) * 136 + col] = f2bf(acc[r][c][i] + bias[ct * 128 + col]);
                }
        }
        __syncthreads();
        #pragma unroll
        for (int it = 0; it < 8; ++it) {      // 128 rows x 16 chunks of 16B
            int linear = tid + it * 256;
            int row = linear >> 4, ch = linear & 15;
            int gr = R0 + row;
            if (gr < M) {
                uint4 v = *reinterpret_cast<const uint4*>(&Cs[row * 136 + ch * 8]);
                ushort_t* dst;
                if (ct == 0)      dst = pack + (size_t)gr * 384 + 256;  // xw
                else if (ct == 1) dst = qb   + (size_t)gr * 128;        // q
                else if (ct == 2) dst = pack + (size_t)gr * 384;        // k
                else if (ct == 3) dst = pack + (size_t)gr * 384 + 128;  // v
                else              dst = xrb  + (size_t)gr * 128;        // x_r
                *reinterpret_cast<uint4*>(dst + ch * 8) = v;
            }
        }
    }
}

// ============ fused FFN1 + FFN2 + residual + LayerNorm2 -> f32 out ============
// hidden [128][256] bf16 lives only in LDS (swizzled); C f32 buffer aliases it.
__device__ __forceinline__ int swz(int ch, int row) {
    return (ch & 24) | ((ch ^ row) & 7);
}

__global__ __launch_bounds__(256)
void ffn_fused(const ushort_t* __restrict__ hlnb,     // [M][128] bf16
               const ushort_t* __restrict__ wt_rel,   // [256][128] bf16
               const ushort_t* __restrict__ wt_root,  // [128][256] bf16
               const float* __restrict__ g2, const float* __restrict__ b2,
               float* __restrict__ outf, int M)
{
    __shared__ float smem[128 * 130];                 // 66.6 KB
    ushort_t* Hs = (ushort_t*)smem;                   // hidden bf16 [128][256] swizzled
    const int tid = threadIdx.x, lane = tid & 63, wid = tid >> 6;
    const int wr = wid >> 1, wc = wid & 1;
    const int R0 = blockIdx.x * 128;

    // ---- FFN1: hidden = relu(hln @ w_rel) -> LDS ----
    short8v av[4][4];
    #pragma unroll
    for (int r = 0; r < 4; ++r) {
        int gr = R0 + wr * 64 + r * 16 + (lane & 15);
        if (gr >= M) gr = M - 1;
        #pragma unroll
        for (int ks = 0; ks < 4; ++ks)
            av[r][ks] = *reinterpret_cast<const short8v*>(
                &hlnb[(size_t)gr * 128 + ks * 32 + (lane >> 4) * 8]);
    }
    for (int ct = 0; ct < 2; ++ct) {
        f32x4 acc[4][4] = {};
        #pragma unroll
        for (int ks = 0; ks < 4; ++ks) {
            short8v bv[4];
            #pragma unroll
            for (int c = 0; c < 4; ++c) {
                int col = ct * 128 + wc * 64 + c * 16 + (lane & 15);
                bv[c] = *reinterpret_cast<const short8v*>(
                    &wt_rel[(size_t)col * 128 + ks * 32 + (lane >> 4) * 8]);
            }
            #pragma unroll
            for (int r = 0; r < 4; ++r)
                #pragma unroll
                for (int c = 0; c < 4; ++c)
                    acc[r][c] = __builtin_amdgcn_mfma_f32_16x16x32_bf16(av[r][ks], bv[c], acc[r][c], 0, 0, 0);
        }
        #pragma unroll
        for (int r = 0; r < 4; ++r) {
            int rowb = wr * 64 + r * 16 + (lane >> 4) * 4;
            #pragma unroll
            for (int i = 0; i < 4; ++i)
                #pragma unroll
                for (int c = 0; c < 4; ++c) {
                    int row = rowb + i;
                    int col = ct * 128 + wc * 64 + c * 16 + (lane & 15);
                    int ch = col >> 3, el = col & 7;
                    Hs[row * 256 + swz(ch, row) * 8 + el] = f2bf(fmaxf(acc[r][c][i], 0.f));
                }
        }
    }
    __syncthreads();

    // ---- FFN2: acc2 = hidden @ w_root ----
    f32x4 acc2[4][4] = {};
    #pragma unroll
    for (int ks = 0; ks < 8; ++ks) {
        short8v a2[4], bv[4];
        #pragma unroll
        for (int r = 0; r < 4; ++r) {
            int row = wr * 64 + r * 16 + (lane & 15);
            int ch = ks * 4 + (lane >> 4);
            a2[r] = *reinterpret_cast<const short8v*>(&Hs[row * 256 + swz(ch, row) * 8]);
        }
        #pragma unroll
        for (int c = 0; c < 4; ++c) {
            int col = wc * 64 + c * 16 + (lane & 15);
            bv[c] = *reinterpret_cast<const short8v*>(
                &wt_root[(size_t)col * 256 + ks * 32 + (lane >> 4) * 8]);
        }
        #pragma unroll
        for (int r = 0; r < 4; ++r)
            #pragma unroll
            for (int c = 0; c < 4; ++c)
                acc2[r][c] = __builtin_amdgcn_mfma_f32_16x16x32_bf16(a2[r], bv[c], acc2[r][c], 0, 0, 0);
    }
    __syncthreads();                          // hidden reads done; reuse as f32 C

    float* Cs = smem;                         // [128][130]
    #pragma unroll
    for (int r = 0; r < 4; ++r) {
        int rowb = wr * 64 + r * 16 + (lane >> 4) * 4;
        #pragma unroll
        for (int i = 0; i < 4; ++i)
            #pragma unroll
            for (int c = 0; c < 4; ++c)
                Cs[(rowb + i) * 130 + wc * 64 + c * 16 + (lane & 15)] = acc2[r][c][i];
    }
    __syncthreads();

    const float ga = g2[lane * 2], gb = g2[lane * 2 + 1];
    const float ba = b2[lane * 2], bb2 = b2[lane * 2 + 1];
    for (int rr = 0; rr < 32; ++rr) {
        int row = wid * 32 + rr;
        int gr = R0 + row;
        if (gr >= M) break;
        unsigned hu = *reinterpret_cast<const unsigned*>(&hlnb[(size_t)gr * 128 + lane * 2]);
        float t0 = Cs[row * 130 + lane * 2]     + bf2f(hu & 0xffffu);
        float t1 = Cs[row * 130 + lane * 2 + 1] + bf2f(hu >> 16);
        float ssum = t0 + t1;
        #pragma unroll
        for (int off = 1; off <= 32; off <<= 1) ssum += __shfl_xor(ssum, off);
        float mu = ssum * (1.f / 128.f);
        float dv0 = t0 - mu, dv1 = t1 - mu;
        float vsum = dv0 * dv0 + dv1 * dv1;
        #pragma unroll
        for (int off = 1; off <= 32; off <<= 1) vsum += __shfl_xor(vsum, off);
        float rs = rsqrtf(vsum * (1.f / 128.f) + EPSV);
        float2 o = make_float2(dv0 * rs * ga + ba, dv1 * rs * gb + bb2);
        *reinterpret_cast<float2*>(&outf[(size_t)gr * 128 + lane * 2]) = o;
    }
}

// =================== weight packing ===================
__global__ void pack_weights_kernel(const float* __restrict__ wg, const float* __restrict__ wq,
                                    const float* __restrict__ wk, const float* __restrict__ wv,
                                    const float* __restrict__ wsk,
                                    const float* __restrict__ bq, const float* __restrict__ bk,
                                    const float* __restrict__ bv, const float* __restrict__ bsk,
                                    const float* __restrict__ wrel, const float* __restrict__ wroot,
                                    ushort_t* __restrict__ wt_all, ushort_t* __restrict__ wt_rel,
                                    ushort_t* __restrict__ wt_root, float* __restrict__ bias_all)
{
    int i = blockIdx.x * 256 + threadIdx.x;
    if (i < 640 * 128) {                         // wt_all[n][k] = W[k][n], 5 concat weights
        int n = i >> 7, k = i & 127;
        const float* srcs[5] = {wg, wq, wk, wv, wsk};
        wt_all[i] = f2bf(srcs[n >> 7][k * 128 + (n & 127)]);
    } else if (i < 640 * 128 + 256 * 128) {      // wt_rel[n][k] = w_rel[k][n]
        int j = i - 640 * 128;
        int n = j >> 7, k = j & 127;
        wt_rel[j] = f2bf(wrel[k * 256 + n]);
    } else if (i < 640 * 128 + 256 * 128 + 128 * 256) {  // wt_root[n][k] = w_root[k][n]
        int j = i - (640 * 128 + 256 * 128);
        int n = j >> 8, k = j & 255;
        wt_root[j] = f2bf(wroot[k * 128 + n]);
    } else if (i < 640 * 128 + 256 * 128 + 128 * 256 + 640) {
        int n = i - (640 * 128 + 256 * 128 + 128 * 256);
        float b = 0.f;                           // cols [0,128) = gcn: bias added in edge kernel
        if (n >= 128) {
            const float* bs[4] = {bq, bk, bv, bsk};
            b = bs[(n - 128) >> 7][n & 127];
        }
        bias_all[n] = b;
    }
}

// =================== graph prep ===================
__global__ void deg_count_kernel(const int* __restrict__ dst, int* __restrict__ deg, int E)
{
    int e = blockIdx.x * blockDim.x + threadIdx.x;
    if (e < E) atomicAdd(&deg[dst[e]], 1);
}

// block-local exclusive scan over chunks of 1024 (256 thr x 4), emits block sums
__global__ __launch_bounds__(256)
void scan1_kernel(const int* __restrict__ deg, int* __restrict__ row_start,
                  int* __restrict__ bsum, int n)
{
    __shared__ int ws[4];
    const int t = threadIdx.x, lane = t & 63, wid = t >> 6;
    const int base = blockIdx.x * 1024 + t * 4;
    int v0 = 0, v1 = 0, v2 = 0, v3 = 0;
    if (base + 3 < n) {
        int4 q = *reinterpret_cast<const int4*>(&deg[base]);
        v0 = q.x; v1 = q.y; v2 = q.z; v3 = q.w;
    } else {
        if (base < n)     v0 = deg[base];
        if (base + 1 < n) v1 = deg[base + 1];
        if (base + 2 < n) v2 = deg[base + 2];
        if (base + 3 < n) v3 = deg[base + 3];
    }
    int tot = v0 + v1 + v2 + v3;
    int inc = tot;
    #pragma unroll
    for (int off = 1; off < 64; off <<= 1) {
        int y = __shfl_up(inc, off);
        if (lane >= off) inc += y;
    }
    if (lane == 63) ws[wid] = inc;
    __syncthreads();
    int woff = 0;
    for (int w = 0; w < wid; ++w) woff += ws[w];
    int excl = woff + inc - tot;
    if (base < n)     row_start[base]     = excl;
    if (base + 1 < n) row_start[base + 1] = excl + v0;
    if (base + 2 < n) row_start[base + 2] = excl + v0 + v1;
    if (base + 3 < n) row_start[base + 3] = excl + v0 + v1 + v2;
    if (t == 0) bsum[blockIdx.x] = ws[0] + ws[1] + ws[2] + ws[3];
}

// single-block exclusive scan of block sums (nb <= 1024)
__global__ __launch_bounds__(256)
void scan2_kernel(int* __restrict__ bsum, int nb)
{
    __shared__ int ws[4];
    const int t = threadIdx.x, lane = t & 63, wid = t >> 6;
    const int base = t * 4;
    int v0 = 0, v1 = 0, v2 = 0, v3 = 0;
    if (base < nb)     v0 = bsum[base];
    if (base + 1 < nb) v1 = bsum[base + 1];
    if (base + 2 < nb) v2 = bsum[base + 2];
    if (base + 3 < nb) v3 = bsum[base + 3];
    int tot = v0 + v1 + v2 + v3;
    int inc = tot;
    #pragma unroll
    for (int off = 1; off < 64; off <<= 1) {
        int y = __shfl_up(inc, off);
        if (lane >= off) inc += y;
    }
    if (lane == 63) ws[wid] = inc;
    __syncthreads();
    int woff = 0;
    for (int w = 0; w < wid; ++w) woff += ws[w];
    int excl = woff + inc - tot;
    if (base < nb)     bsum[base]     = excl;
    if (base + 1 < nb) bsum[base + 1] = excl + v0;
    if (base + 2 < nb) bsum[base + 2] = excl + v0 + v1;
    if (base + 3 < nb) bsum[base + 3] = excl + v0 + v1 + v2;
}

// apply block offsets; also derive cursor, dinv, row_start[n]
__global__ void scan3_kernel(const int* __restrict__ deg, const int* __restrict__ bsum,
                             int* __restrict__ row_start, int* __restrict__ cursor,
                             float* __restrict__ dinv, int n, int E)
{
    int i = blockIdx.x * blockDim.x + threadIdx.x;
    if (i < n) {
        int rs = row_start[i] + bsum[i >> 10];
        row_start[i] = rs;
        cursor[i] = rs;
        int d = deg[i];
        dinv[i] = (d > 0) ? rsqrtf((float)d) : 0.f;
    }
    if (i == 0) row_start[n] = E;
}

__global__ void fill_kernel(const int* __restrict__ src, const int* __restrict__ dst,
                            int* __restrict__ cursor, int* __restrict__ csr_src, int E)
{
    int e = blockIdx.x * blockDim.x + threadIdx.x;
    if (e < E) {
        int d = dst[e];
        int pos = atomicAdd(&cursor[d], 1);
        csr_src[pos] = src[e];
    }
}

// ===== fused: GCN gather + attention + beta gate + combine + LayerNorm1 =====
// pack: [N][384] bf16 = k(128) | v(128) | xw(128). 4 edges in parallel per wave:
// slot = lane>>4 (edge), li = lane&15 (8 dims each). No online max (|alpha| << 1).
__global__ __launch_bounds__(256)
void edge_fused_kernel(const ushort_t* __restrict__ pack,
                       const ushort_t* __restrict__ qbf,
                       const ushort_t* __restrict__ xrbf,
                       const int* __restrict__ row_start,
                       const int* __restrict__ csr_src,
                       const float* __restrict__ dinv,
                       const float* __restrict__ b_gcn,
                       const float* __restrict__ w_beta,
                       const float* __restrict__ g1, const float* __restrict__ b1,
                       const float* __restrict__ local_w, const float* __restrict__ global_w,
                       ushort_t* __restrict__ hln_bf, int n)
{
    const int wid = threadIdx.x >> 6, lane = threadIdx.x & 63;
    const int node = blockIdx.x * 4 + wid;
    if (node >= n) return;
    const int slot = lane >> 4, li = lane & 15;
    const int d8 = li * 8;

    uint4 qu = *reinterpret_cast<const uint4*>(&qbf[(size_t)node * 128 + d8]);
    float q[8];
    #pragma unroll
    for (int i = 0; i < 8; ++i) q[i] = bfp(qu, i);

    const int e0 = row_start[node], e1 = row_start[node + 1];
    const float dn = dinv[node];
    const float scale = 0.17677669529663687f;  // 1/sqrt(32)

    float s = 0.f, va[8] = {}, ga[8] = {};

    for (int j = e0; j < e1; j += 4) {
        const int je = j + slot;
        const bool act = je < e1;
        const int sidx = act ? csr_src[je] : 0;
        const ushort_t* prow = pack + (size_t)sidx * 384;
        uint4 ku = *reinterpret_cast<const uint4*>(&prow[d8]);
        uint4 vu = *reinterpret_cast<const uint4*>(&prow[128 + d8]);
        uint4 xu = *reinterpret_cast<const uint4*>(&prow[256 + d8]);
        float p = 0.f;
        #pragma unroll
        for (int i = 0; i < 8; ++i) p = fmaf(q[i], bfp(ku, i), p);
        p += __shfl_xor(p, 1);                   // head = li>>2 : 4-lane groups
        p += __shfl_xor(p, 2);
        float wgt = act ? __expf(p * scale) : 0.f;
        float c   = act ? dn * dinv[sidx] : 0.f;
        s += wgt;
        #pragma unroll
        for (int i = 0; i < 8; ++i) {
            va[i] = fmaf(wgt, bfp(vu, i), va[i]);
            ga[i] = fmaf(c,   bfp(xu, i), ga[i]);
        }
    }
    // combine the 4 slots (butterfly over lane bits 4,5)
    #pragma unroll
    for (int off = 16; off <= 32; off <<= 1) {
        s += __shfl_xor(s, off);
        #pragma unroll
        for (int i = 0; i < 8; ++i) {
            va[i] += __shfl_xor(va[i], off);
            ga[i] += __shfl_xor(ga[i], off);
        }
    }
    const float denom = fmaxf(s, 1e-16f);        // per-head (head = li>>2)

    uint4 xru = *reinterpret_cast<const uint4*>(&xrbf[(size_t)node * 128 + d8]);
    float t[8];
    float part = 0.f;
    #pragma unroll
    for (int i = 0; i < 8; ++i) {
        float og = va[i] / denom;
        float xr = bfp(xru, i);
        float lo = ga[i] + b_gcn[d8 + i];
        part += og * w_beta[d8 + i] + xr * w_beta[128 + d8 + i]
              + (og - xr) * w_beta[256 + d8 + i];
        t[i] = lo;
        va[i] = og; ga[i] = xr;                   // reuse regs: va=og, ga=xr
    }
    #pragma unroll
    for (int off = 1; off <= 32; off <<= 1) part += __shfl_xor(part, off);
    const float beta = 1.f / (1.f + __expf(-part * 0.25f));   // 4x duplication

    const float lw = local_w[0], gw = global_w[0];
    float ssum = 0.f;
    #pragma unroll
    for (int i = 0; i < 8; ++i) {
        float go = beta * ga[i] + (1.f - beta) * va[i];
        t[i] = 2.f * (lw * t[i] + gw * go);
        ssum += t[i];
    }
    #pragma unroll
    for (int off = 1; off <= 32; off <<= 1) ssum += __shfl_xor(ssum, off);
    const float mu = ssum * (1.f / 512.f);        // 128 dims x4 duplication
    float vsum = 0.f;
    #pragma unroll
    for (int i = 0; i < 8; ++i) { float d = t[i] - mu; vsum += d * d; }
    #pragma unroll
    for (int off = 1; off <= 32; off <<= 1) vsum += __shfl_xor(vsum, off);
    const float rs = rsqrtf(vsum * (1.f / 512.f) + EPSV);

    if (slot == 0) {
        uint4 o;
        #pragma unroll
        for (int i = 0; i < 4; ++i) {
            float o0 = (t[2*i]   - mu) * rs * g1[d8 + 2*i]   + b1[d8 + 2*i];
            float o1 = (t[2*i+1] - mu) * rs * g1[d8 + 2*i+1] + b1[d8 + 2*i+1];
            (&o.x)[i] = (unsigned)f2bf(o0) | ((unsigned)f2bf(o1) << 16);
        }
        *reinterpret_cast<uint4*>(&hln_bf[(size_t)node * 128 + d8]) = o;
    }
}

// =================== launch ===================
extern "C" void kernel_launch(void* const* d_in, const int* in_sizes, int n_in,
                              void* d_out, int out_size, void* d_ws, size_t ws_size,
                              hipStream_t stream)
{
    const float* x      = (const float*)d_in[0];
    const int*   ei     = (const int*)d_in[1];
    const float* w_gcn  = (const float*)d_in[2];
    const float* b_gcn  = (const float*)d_in[3];
    const float* wq     = (const float*)d_in[4];
    const float* bq     = (const float*)d_in[5];
    const float* wk     = (const float*)d_in[6];
    const float* bk     = (const float*)d_in[7];
    const float* wv     = (const float*)d_in[8];
    const float* bv     = (const float*)d_in[9];
    const float* w_skip = (const float*)d_in[10];
    const float* b_skip = (const float*)d_in[11];
    const float* w_beta = (const float*)d_in[12];
    const float* g1     = (const float*)d_in[13];
    const float* b1     = (const float*)d_in[14];
    const float* g2     = (const float*)d_in[15];
    const float* b2     = (const float*)d_in[16];
    const float* w_rel  = (const float*)d_in[17];
    const float* w_root = (const float*)d_in[18];
    const float* lw     = (const float*)d_in[19];
    const float* gw     = (const float*)d_in[20];

    const int N = in_sizes[0] / D;
    const int E = in_sizes[1] / 2;
    const int* src = ei;
    const int* dst = ei + E;

    char* wsb = (char*)d_ws;
    size_t off = 0;
    auto alloc = [&](size_t bytes) -> void* {
        void* p = wsb + off;
        off += (bytes + 255) & ~(size_t)255;
        return p;
    };
    ushort_t* pack_kvx = (ushort_t*)alloc((size_t)N * 384 * 2);  // k|v|xw bf16
    ushort_t* qb_bf    = (ushort_t*)alloc((size_t)N * 128 * 2);
    ushort_t* xr_bf    = (ushort_t*)alloc((size_t)N * 128 * 2);
    ushort_t* hln_bf   = (ushort_t*)alloc((size_t)N * 128 * 2);
    ushort_t* wt_all   = (ushort_t*)alloc(640 * 128 * 2);
    ushort_t* wt_rel   = (ushort_t*)alloc(256 * 128 * 2);
    ushort_t* wt_root  = (ushort_t*)alloc(128 * 256 * 2);
    float*    bias_all = (float*)alloc(640 * 4);
    int*      deg      = (int*)alloc((size_t)N * 4);
    int*      row_start= (int*)alloc((size_t)(N + 1) * 4);
    int*      cursor   = (int*)alloc((size_t)N * 4);
    int*      csr_src  = (int*)alloc((size_t)E * 4);
    float*    dinv     = (float*)alloc((size_t)N * 4);
    int*      bsum     = (int*)alloc(((size_t)(N + 1023) / 1024) * 4);

    float* out = (float*)d_out;
    const int SB = (N + 1023) / 1024;

    // ---- graph prep ----
    hipMemsetAsync(deg, 0, (size_t)N * sizeof(int), stream);
    deg_count_kernel<<<dim3((E + 255) / 256), dim3(256), 0, stream>>>(dst, deg, E);
    scan1_kernel<<<dim3(SB), dim3(256), 0, stream>>>(deg, row_start, bsum, N);
    scan2_kernel<<<dim3(1), dim3(256), 0, stream>>>(bsum, SB);
    scan3_kernel<<<dim3((N + 255) / 256), dim3(256), 0, stream>>>(
        deg, bsum, row_start, cursor, dinv, N, E);
    fill_kernel<<<dim3((E + 255) / 256), dim3(256), 0, stream>>>(src, dst, cursor, csr_src, E);

    // ---- weights ----
    pack_weights_kernel<<<dim3(579), dim3(256), 0, stream>>>(
        w_gcn, wq, wk, wv, w_skip, bq, bk, bv, b_skip, w_rel, w_root,
        wt_all, wt_rel, wt_root, bias_all);

    // ---- fused projections (reads f32 x directly) ----
    const int MB = (N + 127) / 128;
    proj_gemm<<<dim3(MB, 2), dim3(256), 0, stream>>>(
        x, wt_all, bias_all, pack_kvx, qb_bf, xr_bf, N);

    // ---- fused edge phase ----
    edge_fused_kernel<<<dim3((N + 3) / 4), dim3(256), 0, stream>>>(
        pack_kvx, qb_bf, xr_bf, row_start, csr_src, dinv, b_gcn, w_beta,
        g1, b1, lw, gw, hln_bf, N);

    // ---- fused FFN + LN2 ----
    ffn_fused<<<dim3(MB), dim3(256), 0, stream>>>(
        hln_bf, wt_rel, wt_root, g2, b2, out, N);
}